// Round 1
// baseline (15565.106 us; speedup 1.0000x reference)
//
#include <hip/hip_runtime.h>

#define DI 256

static constexpr int Mn  = 50000;
static constexpr int Nn  = 20000;
static constexpr int En  = 200000;
static constexpr int ESn = 100000;

enum { EPI_NONE=0, EPI_ELU1=1, EPI_RELU=2, EPI_DIVZ=3, EPI_LN=4, EPI_LNRES=5 };

// ---------------------------------------------------------------- copy
__global__ __launch_bounds__(256) void copy_f4(const float4* __restrict__ s,
                                               float4* __restrict__ d, long n4) {
  long i = (long)blockIdx.x*blockDim.x + threadIdx.x;
  long st = (long)gridDim.x*blockDim.x;
  for (; i < n4; i += st) d[i] = s[i];
}

// ---------------------------------------------------------------- GEMM (full-width 256)
// C[r, 0:256] = EPI( sum_k A[r,k]*W[k,c] + bias )
// A: k<K0 from A0 (optional row-gather idxA, else dense rows da0+r),
//    k>=K0 from A1 (dense local rows).
// W: k<K0 row k of W0 (ldw0), k>=K0 row k-K0 of W1 (ldw1).
template<int EPI>
__global__ __launch_bounds__(256,2) void gemm256(
    const float* __restrict__ A0, int lda0, const int* __restrict__ idxA, int ga0, int da0,
    const float* __restrict__ A1, int lda1,
    int K, int K0,
    const float* __restrict__ W0, int ldw0, const float* __restrict__ W1, int ldw1,
    const float* __restrict__ bias0, const float* __restrict__ bias1,
    const float* __restrict__ Zr,
    const float* __restrict__ lng, const float* __restrict__ lnb,
    const float* __restrict__ RESB, const int* __restrict__ idxR, int dres0,
    float* __restrict__ C, int ldc, int dc0, int nrows)
{
  __shared__ float As[32][36];    // A^T tile, +4 pad keeps 16B alignment
  __shared__ float Ws[32][256];
  const int t    = threadIdx.x;
  const int col0 = (t & 63) << 2;     // 4 cols per thread; lane==colgroup
  const int rg   = t >> 6;            // wave id = row group
  const int row0 = rg << 3;           // 8 rows per thread
  const int r0   = blockIdx.x << 5;   // 32 rows per block
  const int am   = t >> 3;
  const int ak   = (t & 7) << 2;

  float acc[8][4];
#pragma unroll
  for (int m=0;m<8;++m){ acc[m][0]=0.f;acc[m][1]=0.f;acc[m][2]=0.f;acc[m][3]=0.f; }

  const int nt = K >> 5;
  for (int kt=0; kt<nt; ++kt) {
    const int kb = kt << 5;
    float4 av = make_float4(0.f,0.f,0.f,0.f);
    {
      const int lr = r0 + am;
      if (lr < nrows) {
        const int kg = kb + ak;
        const float* arow; int cx;
        if (kg < K0) {
          long rowi = idxA ? (long)idxA[ga0+lr] : (long)(da0+lr);
          arow = A0 + rowi*(long)lda0; cx = kg;
        } else {
          arow = A1 + (long)lr*lda1; cx = kg - K0;
        }
        av = *(const float4*)(arow + cx);
      }
    }
    float4 wv[8];
#pragma unroll
    for (int i=0;i<8;++i) {
      const int kk = (i<<2) + rg;
      const int kg = kb + kk;
      const float* wrow = (kg < K0) ? (W0 + (long)kg*ldw0) : (W1 + (long)(kg-K0)*ldw1);
      wv[i] = *(const float4*)(wrow + col0);
    }
    __syncthreads();
    As[ak+0][am]=av.x; As[ak+1][am]=av.y; As[ak+2][am]=av.z; As[ak+3][am]=av.w;
#pragma unroll
    for (int i=0;i<8;++i) {
      const int kk = (i<<2) + rg;
      *(float4*)&Ws[kk][col0] = wv[i];
    }
    __syncthreads();
#pragma unroll 8
    for (int k=0;k<32;++k) {
      const float4 w  = *(const float4*)&Ws[k][col0];
      const float4 aL = *(const float4*)&As[k][row0];     // broadcast across wave
      const float4 aH = *(const float4*)&As[k][row0+4];
      const float ar[8] = {aL.x,aL.y,aL.z,aL.w,aH.x,aH.y,aH.z,aH.w};
#pragma unroll
      for (int m=0;m<8;++m){
        acc[m][0]+=ar[m]*w.x; acc[m][1]+=ar[m]*w.y;
        acc[m][2]+=ar[m]*w.z; acc[m][3]+=ar[m]*w.w;
      }
    }
  }

  float4 b0v = make_float4(0.f,0.f,0.f,0.f);
  if (bias0){ const float4 x=*(const float4*)(bias0+col0); b0v.x+=x.x;b0v.y+=x.y;b0v.z+=x.z;b0v.w+=x.w; }
  if (bias1){ const float4 x=*(const float4*)(bias1+col0); b0v.x+=x.x;b0v.y+=x.y;b0v.z+=x.z;b0v.w+=x.w; }
  float4 lgv = make_float4(0,0,0,0), lbv = make_float4(0,0,0,0);
  if constexpr (EPI==EPI_LN || EPI==EPI_LNRES) {
    lgv = *(const float4*)(lng+col0);
    lbv = *(const float4*)(lnb+col0);
  }
#pragma unroll
  for (int m=0;m<8;++m) {
    const int lr = r0 + row0 + m;         // wave-uniform
    if (lr >= nrows) continue;
    float v0=acc[m][0]+b0v.x, v1=acc[m][1]+b0v.y, v2=acc[m][2]+b0v.z, v3=acc[m][3]+b0v.w;
    if constexpr (EPI==EPI_ELU1) {
      v0 = v0>0.f ? v0+1.f : __expf(v0);
      v1 = v1>0.f ? v1+1.f : __expf(v1);
      v2 = v2>0.f ? v2+1.f : __expf(v2);
      v3 = v3>0.f ? v3+1.f : __expf(v3);
    } else if constexpr (EPI==EPI_RELU) {
      v0=fmaxf(v0,0.f); v1=fmaxf(v1,0.f); v2=fmaxf(v2,0.f); v3=fmaxf(v3,0.f);
    } else if constexpr (EPI==EPI_DIVZ) {
      const float iz = 1.f / Zr[lr];
      v0*=iz; v1*=iz; v2*=iz; v3*=iz;
    } else if constexpr (EPI==EPI_LN || EPI==EPI_LNRES) {
      float s = v0+v1+v2+v3;
#pragma unroll
      for (int off=32; off; off>>=1) s += __shfl_xor(s, off);
      const float mu = s*(1.f/256.f);
      v0-=mu; v1-=mu; v2-=mu; v3-=mu;
      float s2 = v0*v0+v1*v1+v2*v2+v3*v3;
#pragma unroll
      for (int off=32; off; off>>=1) s2 += __shfl_xor(s2, off);
      const float rs = rsqrtf(s2*(1.f/256.f) + 1e-5f);
      v0=v0*rs*lgv.x+lbv.x; v1=v1*rs*lgv.y+lbv.y; v2=v2*rs*lgv.z+lbv.z; v3=v3*rs*lgv.w+lbv.w;
      if constexpr (EPI==EPI_LNRES) {
        const long rowi = idxR ? (long)idxR[ga0+lr] : (long)(dres0+lr);
        const float4 rv = *(const float4*)(RESB + rowi*256 + col0);
        v0+=rv.x; v1+=rv.y; v2+=rv.z; v3+=rv.w;
      }
    }
    *(float4*)(C + (long)(dc0+lr)*ldc + col0) = make_float4(v0,v1,v2,v3);
  }
}

// ---------------------------------------------------------------- K^T V split-K partials
// pKV[p][a][b] = sum_{rows in part p} K[r,a]*V[r,b]; pKV[p][65536+a] = colsum K
__global__ __launch_bounds__(256,2) void ktv_partial(
    const float* __restrict__ Kb, const float* __restrict__ Vb,
    int rows, int rpp, float* __restrict__ pKV)
{
  __shared__ float Ks[16][64];
  __shared__ float Vs[16][64];
  const int t = threadIdx.x;
  const int ta = blockIdx.x, tb = blockIdx.y, p = blockIdx.z;
  const int rbeg = p*rpp;
  const int rend = min(rows, rbeg+rpp);
  const int lrow = t >> 4;
  const int lcol = (t & 15) << 2;
  const int a0 = (t & 15) << 2;
  const int b0 = (t >> 4) << 2;
  float acc[4][4];
#pragma unroll
  for (int i=0;i<4;++i) for (int j=0;j<4;++j) acc[i][j]=0.f;
  float ksacc = 0.f;
  for (int r=rbeg; r<rend; r+=16) {
    const int rr = r + lrow;
    float4 kv4 = make_float4(0,0,0,0), vv4 = make_float4(0,0,0,0);
    if (rr < rend) {
      kv4 = *(const float4*)(Kb + (long)rr*256 + ta*64 + lcol);
      vv4 = *(const float4*)(Vb + (long)rr*256 + tb*64 + lcol);
    }
    __syncthreads();
    *(float4*)&Ks[lrow][lcol] = kv4;
    *(float4*)&Vs[lrow][lcol] = vv4;
    __syncthreads();
#pragma unroll 4
    for (int e=0;e<16;++e) {
      const float4 ka = *(const float4*)&Ks[e][a0];
      const float4 vb = *(const float4*)&Vs[e][b0];
      acc[0][0]+=ka.x*vb.x; acc[0][1]+=ka.x*vb.y; acc[0][2]+=ka.x*vb.z; acc[0][3]+=ka.x*vb.w;
      acc[1][0]+=ka.y*vb.x; acc[1][1]+=ka.y*vb.y; acc[1][2]+=ka.y*vb.z; acc[1][3]+=ka.y*vb.w;
      acc[2][0]+=ka.z*vb.x; acc[2][1]+=ka.z*vb.y; acc[2][2]+=ka.z*vb.z; acc[2][3]+=ka.z*vb.w;
      acc[3][0]+=ka.w*vb.x; acc[3][1]+=ka.w*vb.y; acc[3][2]+=ka.w*vb.z; acc[3][3]+=ka.w*vb.w;
    }
    if (tb==0 && t<64) {
      float ks=0.f;
#pragma unroll
      for (int e=0;e<16;++e) ks += Ks[e][t];
      ksacc += ks;
    }
  }
  const long base = (long)p*65792;
#pragma unroll
  for (int i=0;i<4;++i) {
    const int a = ta*64 + a0 + i;
    *(float4*)&pKV[base + (long)a*256 + tb*64 + b0] = make_float4(acc[i][0],acc[i][1],acc[i][2],acc[i][3]);
  }
  if (tb==0 && t<64) pKV[base + 65536 + ta*64 + t] = ksacc;
}

__global__ __launch_bounds__(256) void kv_accum(const float* __restrict__ pKV, int P,
                                                float* __restrict__ KV) {
  const int i = blockIdx.x*256 + threadIdx.x;
  if (i >= 65792) return;
  float s = 0.f;
  for (int p=0;p<P;++p) s += pKV[(long)p*65792 + i];
  KV[i] += s;
}

// Z[r] = Q[r,:] . Ksum + 1e-6  (one wave per row)
__global__ __launch_bounds__(256) void row_dot(const float* __restrict__ Q,
    const float* __restrict__ Ksum, float* __restrict__ Z, int rows) {
  const long gid = (long)blockIdx.x*256 + threadIdx.x;
  const int row = (int)(gid >> 6);
  const int lane = (int)(gid & 63);
  if (row >= rows) return;
  const float4 q = *(const float4*)(Q + (long)row*256 + lane*4);
  const float4 k = *(const float4*)(Ksum + lane*4);
  float s = q.x*k.x + q.y*k.y + q.z*k.z + q.w*k.w;
#pragma unroll
  for (int off=32; off; off>>=1) s += __shfl_xor(s, off);
  if (lane==0) Z[row] = s + 1e-6f;
}

// Conv1d(2->1, k=3, pad=1) over gathered src/dst rows of ORIGINAL h_nodes
__global__ __launch_bounds__(256) void conv_rows(const float* __restrict__ h,
    const int* __restrict__ gs, const int* __restrict__ gd, int gr0, int rows,
    const float* __restrict__ cw, const float* __restrict__ cb, float* __restrict__ Cc) {
  const int r = blockIdx.x;
  if (r >= rows) return;
  const int d = threadIdx.x;
  const float* sr = h + (long)gs[gr0+r]*256;
  const float* dr = h + (long)gd[gr0+r]*256;
  const float sm = d>0   ? sr[d-1] : 0.f;
  const float sp = d<255 ? sr[d+1] : 0.f;
  const float dm = d>0   ? dr[d-1] : 0.f;
  const float dp = d<255 ? dr[d+1] : 0.f;
  Cc[(long)r*256 + d] = cb[0] + cw[0]*sm + cw[1]*sr[d] + cw[2]*sp
                              + cw[3]*dm + cw[4]*dr[d] + cw[5]*dp;
}

// ---------------------------------------------------------------- BatchNorm (train)
__global__ __launch_bounds__(256) void bn_stats(const float* __restrict__ X, long rows,
    int rpb, float* __restrict__ part) {
  const int p = blockIdx.x;
  const int c = threadIdx.x;
  long r0 = (long)p*rpb;
  long r1 = r0 + rpb; if (r1 > rows) r1 = rows;
  float s=0.f, s2=0.f;
  for (long r=r0; r<r1; ++r) { const float v = X[r*256 + c]; s += v; s2 += v*v; }
  part[(long)p*512 + c] = s;
  part[(long)p*512 + 256 + c] = s2;
}

__global__ __launch_bounds__(256) void bn_finalize(const float* __restrict__ part, int P,
    long rows, const float* __restrict__ g, const float* __restrict__ b,
    float* __restrict__ scale, float* __restrict__ shift) {
  const int c = threadIdx.x;
  float s=0.f, s2=0.f;
  for (int p=0;p<P;++p) { s += part[(long)p*512 + c]; s2 += part[(long)p*512 + 256 + c]; }
  const float inv = 1.f/(float)rows;
  const float mu = s*inv;
  float var = s2*inv - mu*mu;
  var = var > 0.f ? var : 0.f;
  const float rs = rsqrtf(var + 1e-5f);
  scale[c] = g[c]*rs;
  shift[c] = b[c] - mu*g[c]*rs;
}

template<bool R>
__global__ __launch_bounds__(256) void bn_apply(float* __restrict__ X, long rows,
    const float* __restrict__ sc, const float* __restrict__ sh) {
  const long n4 = rows*64;
  long i = (long)blockIdx.x*256 + threadIdx.x;
  const long st = (long)gridDim.x*256;
  for (; i<n4; i+=st) {
    const int cq = (int)(i & 63);
    float4 v = ((float4*)X)[i];
    const float4 s4 = ((const float4*)sc)[cq];
    const float4 h4 = ((const float4*)sh)[cq];
    v.x = v.x*s4.x + h4.x; v.y = v.y*s4.y + h4.y;
    v.z = v.z*s4.z + h4.z; v.w = v.w*s4.w + h4.w;
    if (R) { v.x=fmaxf(v.x,0.f); v.y=fmaxf(v.y,0.f); v.z=fmaxf(v.z,0.f); v.w=fmaxf(v.w,0.f); }
    ((float4*)X)[i] = v;
  }
}

// ---------------------------------------------------------------- host-side encoder
struct EncArgs {
  const float *Wq,*Wk,*Wv,*Wm,*bm,*l1g,*l1b,*mw1,*mb1,*mw2,*mb2,*l2g,*l2b;
  float *B1,*B2,*B3,*Zb,*pKV,*KV;
  long CH;
};

static void run_enc(long L, long S,
                    const float* Ab, const int* iA, int Aoff,
                    const float* Bb, const int* iB, int Boff,
                    float* dst, const EncArgs& e, hipStream_t st)
{
  hipMemsetAsync(e.KV, 0, 65792*sizeof(float), st);
  // phase A: stream K,V chunks, accumulate KV = K^T V and Ksum
  for (long s0=0; s0<S; s0+=e.CH) {
    const int cnt = (int)((S-s0 < e.CH) ? (S-s0) : e.CH);
    const int gb = (cnt+31)/32;
    gemm256<EPI_ELU1><<<gb,256,0,st>>>(Bb,DI,iB,(int)s0,Boff+(int)s0, nullptr,0, 256,256,
        e.Wk,DI,nullptr,0, nullptr,nullptr, nullptr, nullptr,nullptr, nullptr,nullptr,0,
        e.B1,DI,0,cnt);
    gemm256<EPI_NONE><<<gb,256,0,st>>>(Bb,DI,iB,(int)s0,Boff+(int)s0, nullptr,0, 256,256,
        e.Wv,DI,nullptr,0, nullptr,nullptr, nullptr, nullptr,nullptr, nullptr,nullptr,0,
        e.B2,DI,0,cnt);
    const int P = (cnt+1023)/1024;
    ktv_partial<<<dim3(4,4,P),256,0,st>>>(e.B1,e.B2,cnt,1024,e.pKV);
    kv_accum<<<257,256,0,st>>>(e.pKV,P,e.KV);
  }
  // phase B: per L-chunk Q -> Z -> msg0 -> msg(LN) -> MLP -> out(LN+res)
  for (long l0=0; l0<L; l0+=e.CH) {
    const int cnt = (int)((L-l0 < e.CH) ? (L-l0) : e.CH);
    const int gb = (cnt+31)/32;
    gemm256<EPI_ELU1><<<gb,256,0,st>>>(Ab,DI,iA,(int)l0,Aoff+(int)l0, nullptr,0, 256,256,
        e.Wq,DI,nullptr,0, nullptr,nullptr, nullptr, nullptr,nullptr, nullptr,nullptr,0,
        e.B1,DI,0,cnt);
    row_dot<<<(cnt+3)/4,256,0,st>>>(e.B1, e.KV+65536, e.Zb, cnt);
    gemm256<EPI_DIVZ><<<gb,256,0,st>>>(e.B1,DI,nullptr,0,0, nullptr,0, 256,256,
        e.KV,DI,nullptr,0, nullptr,nullptr, e.Zb, nullptr,nullptr, nullptr,nullptr,0,
        e.B2,DI,0,cnt);
    gemm256<EPI_LN><<<gb,256,0,st>>>(e.B2,DI,nullptr,0,0, nullptr,0, 256,256,
        e.Wm,DI,nullptr,0, e.bm,nullptr, nullptr, e.l1g,e.l1b, nullptr,nullptr,0,
        e.B3,DI,0,cnt);
    // y1 = relu([x,msg]@mw1 + mb1), written as [cnt,512] across B1|B2
    gemm256<EPI_RELU><<<gb,256,0,st>>>(Ab,DI,iA,(int)l0,Aoff+(int)l0, e.B3,DI, 512,256,
        e.mw1,512, e.mw1+(long)256*512,512, e.mb1,nullptr, nullptr, nullptr,nullptr, nullptr,nullptr,0,
        e.B1,512,0,cnt);
    gemm256<EPI_RELU><<<gb,256,0,st>>>(Ab,DI,iA,(int)l0,Aoff+(int)l0, e.B3,DI, 512,256,
        e.mw1+256,512, e.mw1+(long)256*512+256,512, e.mb1+256,nullptr, nullptr, nullptr,nullptr, nullptr,nullptr,0,
        e.B1+256,512,0,cnt);
    // out = x + LN(y1@mw2 + mb2)
    gemm256<EPI_LNRES><<<gb,256,0,st>>>(e.B1,512,nullptr,(int)l0,0, nullptr,0, 512,512,
        e.mw2,DI,nullptr,0, e.mb2,nullptr, nullptr, e.l2g,e.l2b, Ab,iA,Aoff+(int)l0,
        dst,DI,(int)l0,cnt);
  }
}

// ---------------------------------------------------------------- launch
extern "C" void kernel_launch(void* const* d_in, const int* in_sizes, int n_in,
                              void* d_out, int out_size, void* d_ws, size_t ws_size,
                              hipStream_t stream) {
  const float* h_nodes = (const float*)d_in[0];
  const float* s_u     = (const float*)d_in[1];
  const int*   g_src   = (const int*)d_in[2];
  const int*   g_dst   = (const int*)d_in[3];
  const int*   s_src   = (const int*)d_in[4];
  const int*   s_dst   = (const int*)d_in[5];
  const float* conv_w  = (const float*)d_in[6];
  const float* conv_b  = (const float*)d_in[7];
  const float* W2      = (const float*)d_in[8];
  const float* b2      = (const float*)d_in[9];
  const float* W4      = (const float*)d_in[10];
  const float* b4      = (const float*)d_in[11];
  const float* bn_g    = (const float*)d_in[12];
  const float* bn_b    = (const float*)d_in[13];
  const float* Wq      = (const float*)d_in[14];
  const float* Wk      = (const float*)d_in[15];
  const float* Wv      = (const float*)d_in[16];
  const float* Wm      = (const float*)d_in[17];
  const float* bm      = (const float*)d_in[18];
  const float* l1g     = (const float*)d_in[19];
  const float* l1b     = (const float*)d_in[20];
  const float* mw1     = (const float*)d_in[21];
  const float* mb1     = (const float*)d_in[22];
  const float* mw2     = (const float*)d_in[23];
  const float* mb2     = (const float*)d_in[24];
  const float* l2g     = (const float*)d_in[25];
  const float* l2b     = (const float*)d_in[26];
  (void)in_sizes; (void)n_in; (void)out_size;

  float* outp = (float*)d_out;
  float* lr_e = outp;                        // [E,256] pre-BN staging then final
  float* soc  = outp + (size_t)En*DI;        // [ES,256]

  // ---- carve workspace (all sizes 256B-aligned)
  char* base = (char*)d_ws;
  size_t off = 0;
  auto carve = [&](size_t bytes)->float* {
    float* p = (float*)(base + off);
    off = (off + bytes + 255) & ~(size_t)255;
    return p;
  };
  float* h_n     = carve((size_t)Mn*DI*4);       // h_nodes with rows[0:N] replaced by x
  float* KV      = carve(65792*4);               // KV[256][256] + Ksum[256]
  float* bnpart  = carve((size_t)512*512*4);
  float* bnscale = carve(256*4);
  float* bnshift = carve(256*4);
  const size_t remain = ws_size > off ? ws_size - off : 0;
  // bytes per 1024 rows: 3 chunk bufs (3*1024*1024) + Z (4096) + pKV part (65792*4)
  long CH = (long)(remain / 3412992) * 1024;
  if (CH > 200704) CH = 200704;
  if (CH < 2048)   CH = 2048;
  float* B1  = carve((size_t)CH*DI*4);
  float* B2  = carve((size_t)CH*DI*4);           // contiguous with B1 (y1 spans both)
  float* B3  = carve((size_t)CH*DI*4);
  float* Zb  = carve((size_t)CH*4);
  const int PMAX = (int)((CH+1023)/1024);
  float* pKV = carve((size_t)PMAX*65792*4);

  // ---- 1. h_n = h_nodes (rows [0:N) overwritten by encoder 1 below)
  copy_f4<<<2048,256,0,stream>>>((const float4*)h_nodes, (float4*)h_n, (long)Mn*64);

  EncArgs e{Wq,Wk,Wv,Wm,bm,l1g,l1b,mw1,mb1,mw2,mb2,l2g,l2b, B1,B2,B3,Zb,pKV,KV,CH};

  // ---- 2. x = enc(h_nodes[:N], s_u) -> h_n[0:N]
  run_enc(Nn, Nn, h_nodes, nullptr, 0, s_u, nullptr, 0, h_n, e, stream);
  // ---- 3. edge = enc(h_n[g_src], h_n[g_dst]) -> lr_e (pre-W4)
  run_enc(En, En, h_n, g_src, 0, h_n, g_dst, 0, lr_e, e, stream);
  // ---- 4. social = enc(x[s_src], x[s_dst]) -> soc (pre-BN)
  run_enc(ESn, ESn, h_n, s_src, 0, h_n, s_dst, 0, soc, e, stream);

  // ---- 5. lr_e = edge@W4 + conv@W2 + b4 + b2   (in place, conv per chunk)
  for (long e0=0; e0<En; e0+=CH) {
    const int cnt = (int)(((long)En-e0 < CH) ? (En-e0) : CH);
    conv_rows<<<cnt,256,0,stream>>>(h_nodes, g_src, g_dst, (int)e0, cnt, conv_w, conv_b, B3);
    const int gb = (cnt+31)/32;
    gemm256<EPI_NONE><<<gb,256,0,stream>>>(lr_e,DI,nullptr,0,(int)e0, B3,DI, 512,256,
        W4,DI, W2,DI, b4,b2, nullptr, nullptr,nullptr, nullptr,nullptr,0,
        lr_e,DI,(int)e0,cnt);
  }

  // ---- 6. lr_e = relu(BN(lr_e))
  {
    const int P3 = (En+511)/512;
    bn_stats<<<P3,256,0,stream>>>(lr_e,(long)En,512,bnpart);
    bn_finalize<<<1,256,0,stream>>>(bnpart,P3,(long)En,bn_g,bn_b,bnscale,bnshift);
    bn_apply<true><<<2048,256,0,stream>>>(lr_e,(long)En,bnscale,bnshift);
  }
  // ---- 7. soc = BN(soc)
  {
    const int P4 = (ESn+511)/512;
    bn_stats<<<P4,256,0,stream>>>(soc,(long)ESn,512,bnpart);
    bn_finalize<<<1,256,0,stream>>>(bnpart,P4,(long)ESn,bn_g,bn_b,bnscale,bnshift);
    bn_apply<false><<<2048,256,0,stream>>>(soc,(long)ESn,bnscale,bnshift);
  }
}

// Round 2
// 3399.786 us; speedup vs baseline: 4.5783x; 4.5783x over previous
//
#include <hip/hip_runtime.h>

static constexpr int Mn  = 50000;
static constexpr int Nn  = 20000;
static constexpr int En  = 200000;
static constexpr int ESn = 100000;

typedef short short8v __attribute__((ext_vector_type(8)));
typedef short short4v __attribute__((ext_vector_type(4)));
typedef float f32x4   __attribute__((ext_vector_type(4)));

enum { EPI_NONE=0, EPI_ELU1=1, EPI_RELU=2, EPI_DIVZ=3, EPI_LN=4, EPI_LNRES=5 };

__device__ __forceinline__ float b2f(unsigned short h) {
  unsigned int u = ((unsigned int)h) << 16;
  return __builtin_bit_cast(float, u);
}
__device__ __forceinline__ unsigned short f2b(float f) {
  unsigned int u = __builtin_bit_cast(unsigned int, f);
  u = (u + 0x7FFFu + ((u >> 16) & 1u)) >> 16;
  return (unsigned short)u;
}

// ---------------------------------------------------------------- fp32 -> bf16 flat convert
__global__ __launch_bounds__(256) void cvt_b(const float* __restrict__ s,
                                             unsigned short* __restrict__ d, long n) {
  long g  = (long)blockIdx.x*256 + threadIdx.x;
  long st = (long)gridDim.x*256;
  for (; g*8 < n; g += st) {
    const float4 a = *(const float4*)(s + g*8);
    const float4 b = *(const float4*)(s + g*8 + 4);
    short8v o;
    o[0]=(short)f2b(a.x); o[1]=(short)f2b(a.y); o[2]=(short)f2b(a.z); o[3]=(short)f2b(a.w);
    o[4]=(short)f2b(b.x); o[5]=(short)f2b(b.y); o[6]=(short)f2b(b.z); o[7]=(short)f2b(b.w);
    *(short8v*)(d + g*8) = o;
  }
}

// ---------------------------------------------------------------- W [K][N] fp32 -> WT[n*ldo + koff + k] bf16
__global__ __launch_bounds__(256) void wt_build(const float* __restrict__ W, int K, int N,
    unsigned short* __restrict__ WT, int ldo, int koff) {
  __shared__ unsigned short T[64][72];
  const int t  = threadIdx.x;
  const int n0 = blockIdx.x << 6, k0 = blockIdx.y << 6;
  const int kr = t >> 2, nc = (t & 3) << 4;
#pragma unroll
  for (int j = 0; j < 16; j += 4) {
    float4 v = *(const float4*)(W + (long)(k0+kr)*N + n0 + nc + j);
    T[kr][nc+j+0]=f2b(v.x); T[kr][nc+j+1]=f2b(v.y);
    T[kr][nc+j+2]=f2b(v.z); T[kr][nc+j+3]=f2b(v.w);
  }
  __syncthreads();
  const int nr = t >> 2, kc = (t & 3) << 4;
  unsigned short tmp[16];
#pragma unroll
  for (int j = 0; j < 16; ++j) tmp[j] = T[kc+j][nr];
  unsigned short* o = WT + (long)(n0+nr)*ldo + koff + k0 + kc;
  short8v u0, u1;
#pragma unroll
  for (int j = 0; j < 8; ++j) { u0[j] = (short)tmp[j]; u1[j] = (short)tmp[8+j]; }
  *(short8v*)o       = u0;
  *(short8v*)(o + 8) = u1;
}

// ---------------------------------------------------------------- MFMA GEMM, full-width 256 cols
// C[r, 0:256] = EPI( sum_k A[r,k]*W[k,c] + bias ), W given transposed: WT[c][k]
// A: k<K0 from A0 (optional row-gather idxA, rows aoff+lr), k>=K0 from A1 (dense local rows)
template<int EPI, bool OBF16>
__global__ __launch_bounds__(256,2) void gemm_mf(
    const unsigned short* __restrict__ A0, int lda0,
    const int* __restrict__ idxA, int aoff,
    const unsigned short* __restrict__ A1, int lda1,
    int K, int K0,
    const unsigned short* __restrict__ WT, int ldwt,
    const float* __restrict__ bias0, const float* __restrict__ bias1,
    const float* __restrict__ Zr,
    const float* __restrict__ lng, const float* __restrict__ lnb,
    const unsigned short* RESB, const int* __restrict__ idxR, int roff,
    void* Cv, int ldc, int dc0, int nrows)
{
  __shared__ short As[64*64];
  __shared__ short Bs[256*64];
  __shared__ float2 red[64][5];

  const int t    = threadIdx.x;
  const int w    = t >> 6;
  const int lane = t & 63;
  const int q    = lane >> 4;
  const int hw   = lane & 15;
  const int r0   = blockIdx.x << 6;

  // staging roles: thread t stages A row (t>>2), 32 bytes; B row n=t, 128 bytes
  const int arow = t >> 2;
  const int akc  = (t & 3) << 1;
  const int alr  = r0 + arow;
  const bool avalid = alr < nrows;
  long arid = 0;
  if (avalid) arid = idxA ? (long)idxA[aoff + alr] : (long)(aoff + alr);

  f32x4 acc[4][4];
#pragma unroll
  for (int m=0;m<4;++m)
#pragma unroll
    for (int n=0;n<4;++n) acc[m][n] = (f32x4){0.f,0.f,0.f,0.f};

  for (int kb = 0; kb < K; kb += 64) {
    short8v av0 = {0,0,0,0,0,0,0,0}, av1 = {0,0,0,0,0,0,0,0};
    if (avalid) {
      const unsigned short* ap;
      if (kb < K0) ap = A0 + arid*(long)lda0 + kb + ((t&3)<<4);
      else         ap = A1 + (long)alr*lda1 + (kb - K0) + ((t&3)<<4);
      av0 = *(const short8v*)ap;
      av1 = *(const short8v*)(ap + 8);
    }
    short8v bv[8];
    const unsigned short* bp = WT + (long)t*ldwt + kb;
#pragma unroll
    for (int j=0;j<8;++j) bv[j] = *(const short8v*)(bp + j*8);

    __syncthreads();
    *(short8v*)&As[arow*64 + (((akc  ) ^ (arow&7))<<3)] = av0;
    *(short8v*)&As[arow*64 + (((akc+1) ^ (arow&7))<<3)] = av1;
#pragma unroll
    for (int j=0;j<8;++j)
      *(short8v*)&Bs[t*64 + ((j ^ (t&7))<<3)] = bv[j];
    __syncthreads();

#pragma unroll
    for (int kk=0;kk<2;++kk) {
      const int kc = (kk<<2) + q;
      short8v af[4], bf[4];
#pragma unroll
      for (int m=0;m<4;++m)
        af[m] = *(const short8v*)&As[(m*16+hw)*64 + ((kc ^ (hw&7))<<3)];
#pragma unroll
      for (int n=0;n<4;++n)
        bf[n] = *(const short8v*)&Bs[(w*64+n*16+hw)*64 + ((kc ^ (hw&7))<<3)];
#pragma unroll
      for (int m=0;m<4;++m)
#pragma unroll
        for (int n=0;n<4;++n)
          acc[m][n] = __builtin_amdgcn_mfma_f32_16x16x32_bf16(af[m], bf[n], acc[m][n], 0,0,0);
    }
  }

  // ---------------- epilogue ----------------
  float bia[4] = {0.f,0.f,0.f,0.f};
#pragma unroll
  for (int n=0;n<4;++n) {
    const int c = w*64 + n*16 + hw;
    if (bias0) bia[n] += bias0[c];
    if (bias1) bia[n] += bias1[c];
  }
#pragma unroll
  for (int m=0;m<4;++m)
#pragma unroll
    for (int n=0;n<4;++n)
#pragma unroll
      for (int i=0;i<4;++i) acc[m][n][i] += bia[n];

  if constexpr (EPI == EPI_ELU1) {
#pragma unroll
    for (int m=0;m<4;++m)
#pragma unroll
      for (int n=0;n<4;++n)
#pragma unroll
        for (int i=0;i<4;++i) {
          float v = acc[m][n][i];
          acc[m][n][i] = v > 0.f ? v + 1.f : __expf(v);
        }
  }
  if constexpr (EPI == EPI_RELU) {
#pragma unroll
    for (int m=0;m<4;++m)
#pragma unroll
      for (int n=0;n<4;++n)
#pragma unroll
        for (int i=0;i<4;++i) acc[m][n][i] = fmaxf(acc[m][n][i], 0.f);
  }
  if constexpr (EPI == EPI_DIVZ) {
#pragma unroll
    for (int m=0;m<4;++m) {
      f32x4 z = *(const f32x4*)(Zr + r0 + m*16 + q*4);
#pragma unroll
      for (int i=0;i<4;++i) {
        const float iz = 1.f / z[i];
#pragma unroll
        for (int n=0;n<4;++n) acc[m][n][i] *= iz;
      }
    }
  }

  float mu[4][4], rsg[4][4];
  float lg[4], lb[4];
  if constexpr (EPI == EPI_LN || EPI == EPI_LNRES) {
#pragma unroll
    for (int n=0;n<4;++n) {
      const int c = w*64 + n*16 + hw;
      lg[n] = lng[c]; lb[n] = lnb[c];
    }
    float s1[4][4], s2[4][4];
#pragma unroll
    for (int m=0;m<4;++m)
#pragma unroll
      for (int i=0;i<4;++i) {
        float s = 0.f, sq = 0.f;
#pragma unroll
        for (int n=0;n<4;++n) { const float v = acc[m][n][i]; s += v; sq += v*v; }
        s1[m][i] = s; s2[m][i] = sq;
      }
#pragma unroll
    for (int off=1; off<16; off<<=1)
#pragma unroll
      for (int m=0;m<4;++m)
#pragma unroll
        for (int i=0;i<4;++i) {
          s1[m][i] += __shfl_xor(s1[m][i], off);
          s2[m][i] += __shfl_xor(s2[m][i], off);
        }
    if (hw == 0) {
#pragma unroll
      for (int m=0;m<4;++m)
#pragma unroll
        for (int i=0;i<4;++i)
          red[m*16 + q*4 + i][w] = make_float2(s1[m][i], s2[m][i]);
    }
    __syncthreads();
#pragma unroll
    for (int m=0;m<4;++m)
#pragma unroll
      for (int i=0;i<4;++i) {
        float ts = 0.f, tq = 0.f;
#pragma unroll
        for (int ww=0;ww<4;++ww) {
          const float2 v = red[m*16 + q*4 + i][ww];
          ts += v.x; tq += v.y;
        }
        const float mmu = ts * (1.f/256.f);
        float var = tq * (1.f/256.f) - mmu*mmu;
        var = var > 0.f ? var : 0.f;
        mu[m][i]  = mmu;
        rsg[m][i] = rsqrtf(var + 1e-5f);
      }
  }

#pragma unroll
  for (int m=0;m<4;++m) {
#pragma unroll
    for (int i=0;i<4;++i) {
      const int rr = m*16 + q*4 + i;
      const int lr = r0 + rr;
      if (lr >= nrows) continue;
      long rid = 0;
      if constexpr (EPI == EPI_LNRES)
        rid = idxR ? (long)idxR[roff + lr] : (long)(roff + lr);
#pragma unroll
      for (int n=0;n<4;++n) {
        const int c = w*64 + n*16 + hw;
        float v = acc[m][n][i];
        if constexpr (EPI == EPI_LN || EPI == EPI_LNRES)
          v = (v - mu[m][i]) * rsg[m][i] * lg[n] + lb[n];
        if constexpr (EPI == EPI_LNRES)
          v += b2f(RESB[rid*256 + c]);
        const long coff = (long)(dc0 + lr)*ldc + c;
        if constexpr (OBF16) ((unsigned short*)Cv)[coff] = f2b(v);
        else                 ((float*)Cv)[coff] = v;
      }
    }
  }
}

// ---------------------------------------------------------------- K^T V split-K partials (VALU fp32, bf16 in)
__global__ __launch_bounds__(256,2) void ktv_partial(
    const unsigned short* __restrict__ Kb, const unsigned short* __restrict__ Vb,
    int rows, int rpp, float* __restrict__ pKV)
{
  __shared__ float Ks[16][64];
  __shared__ float Vs[16][64];
  const int t = threadIdx.x;
  const int ta = blockIdx.x, tb = blockIdx.y, p = blockIdx.z;
  const int rbeg = p*rpp;
  const int rend = min(rows, rbeg+rpp);
  const int lrow = t >> 4;
  const int lcol = (t & 15) << 2;
  const int a0 = (t & 15) << 2;
  const int b0 = (t >> 4) << 2;
  float acc[4][4];
#pragma unroll
  for (int i=0;i<4;++i)
#pragma unroll
    for (int j=0;j<4;++j) acc[i][j]=0.f;
  float ksacc = 0.f;
  for (int r=rbeg; r<rend; r+=16) {
    const int rr = r + lrow;
    float kv[4] = {0,0,0,0}, vv[4] = {0,0,0,0};
    if (rr < rend) {
      short4v k4 = *(const short4v*)(Kb + (long)rr*256 + ta*64 + lcol);
      short4v v4 = *(const short4v*)(Vb + (long)rr*256 + tb*64 + lcol);
#pragma unroll
      for (int j=0;j<4;++j) { kv[j]=b2f((unsigned short)k4[j]); vv[j]=b2f((unsigned short)v4[j]); }
    }
    __syncthreads();
#pragma unroll
    for (int j=0;j<4;++j) { Ks[lrow][lcol+j]=kv[j]; Vs[lrow][lcol+j]=vv[j]; }
    __syncthreads();
#pragma unroll 4
    for (int e=0;e<16;++e) {
      const float4 ka = *(const float4*)&Ks[e][a0];
      const float4 vb = *(const float4*)&Vs[e][b0];
      acc[0][0]+=ka.x*vb.x; acc[0][1]+=ka.x*vb.y; acc[0][2]+=ka.x*vb.z; acc[0][3]+=ka.x*vb.w;
      acc[1][0]+=ka.y*vb.x; acc[1][1]+=ka.y*vb.y; acc[1][2]+=ka.y*vb.z; acc[1][3]+=ka.y*vb.w;
      acc[2][0]+=ka.z*vb.x; acc[2][1]+=ka.z*vb.y; acc[2][2]+=ka.z*vb.z; acc[2][3]+=ka.z*vb.w;
      acc[3][0]+=ka.w*vb.x; acc[3][1]+=ka.w*vb.y; acc[3][2]+=ka.w*vb.z; acc[3][3]+=ka.w*vb.w;
    }
    if (tb==0 && t<64) {
      float ks=0.f;
#pragma unroll
      for (int e=0;e<16;++e) ks += Ks[e][t];
      ksacc += ks;
    }
  }
  const long base = (long)p*65792;
#pragma unroll
  for (int i=0;i<4;++i) {
    const int a = ta*64 + a0 + i;
    *(float4*)&pKV[base + (long)a*256 + tb*64 + b0] =
        make_float4(acc[i][0],acc[i][1],acc[i][2],acc[i][3]);
  }
  if (tb==0 && t<64) pKV[base + 65536 + ta*64 + t] = ksacc;
}

__global__ __launch_bounds__(256) void kv_accum(const float* __restrict__ pKV, int P,
                                                float* __restrict__ KV) {
  const int i = blockIdx.x*256 + threadIdx.x;
  if (i >= 65792) return;
  float s = 0.f;
  for (int p=0;p<P;++p) s += pKV[(long)p*65792 + i];
  KV[i] += s;
}

// Z[r] = Q[r,:] . Ksum + 1e-6  (one wave per row, Q bf16)
__global__ __launch_bounds__(256) void row_dot(const unsigned short* __restrict__ Q,
    const float* __restrict__ Ksum, float* __restrict__ Z, int rows) {
  const long gid = (long)blockIdx.x*256 + threadIdx.x;
  const int row = (int)(gid >> 6);
  const int lane = (int)(gid & 63);
  if (row >= rows) return;
  short4v q4 = *(const short4v*)(Q + (long)row*256 + lane*4);
  const float4 k = *(const float4*)(Ksum + lane*4);
  float s = b2f((unsigned short)q4[0])*k.x + b2f((unsigned short)q4[1])*k.y
          + b2f((unsigned short)q4[2])*k.z + b2f((unsigned short)q4[3])*k.w;
#pragma unroll
  for (int off=32; off; off>>=1) s += __shfl_xor(s, off);
  if (lane==0) Z[row] = s + 1e-6f;
}

// Conv1d(2->1, k=3, pad=1) over gathered src/dst rows of ORIGINAL h_nodes -> bf16
__global__ __launch_bounds__(256) void conv_rows(const float* __restrict__ h,
    const int* __restrict__ gs, const int* __restrict__ gd, int gr0, int rows,
    const float* __restrict__ cw, const float* __restrict__ cb,
    unsigned short* __restrict__ Cc) {
  const int r = blockIdx.x;
  if (r >= rows) return;
  const int d = threadIdx.x;
  const float* sr = h + (long)gs[gr0+r]*256;
  const float* dr = h + (long)gd[gr0+r]*256;
  const float sm = d>0   ? sr[d-1] : 0.f;
  const float sp = d<255 ? sr[d+1] : 0.f;
  const float dm = d>0   ? dr[d-1] : 0.f;
  const float dp = d<255 ? dr[d+1] : 0.f;
  Cc[(long)r*256 + d] = f2b(cb[0] + cw[0]*sm + cw[1]*sr[d] + cw[2]*sp
                                  + cw[3]*dm + cw[4]*dr[d] + cw[5]*dp);
}

// ---------------------------------------------------------------- BatchNorm (train), fp32 in place
__global__ __launch_bounds__(256) void bn_stats(const float* __restrict__ X, long rows,
    int rpb, float* __restrict__ part) {
  const int p = blockIdx.x;
  const int c = threadIdx.x;
  long r0 = (long)p*rpb;
  long r1 = r0 + rpb; if (r1 > rows) r1 = rows;
  float s=0.f, s2=0.f;
  for (long r=r0; r<r1; ++r) { const float v = X[r*256 + c]; s += v; s2 += v*v; }
  part[(long)p*512 + c] = s;
  part[(long)p*512 + 256 + c] = s2;
}

__global__ __launch_bounds__(256) void bn_finalize(const float* __restrict__ part, int P,
    long rows, const float* __restrict__ g, const float* __restrict__ b,
    float* __restrict__ scale, float* __restrict__ shift) {
  const int c = threadIdx.x;
  float s=0.f, s2=0.f;
  for (int p=0;p<P;++p) { s += part[(long)p*512 + c]; s2 += part[(long)p*512 + 256 + c]; }
  const float inv = 1.f/(float)rows;
  const float mu = s*inv;
  float var = s2*inv - mu*mu;
  var = var > 0.f ? var : 0.f;
  const float rs = rsqrtf(var + 1e-5f);
  scale[c] = g[c]*rs;
  shift[c] = b[c] - mu*g[c]*rs;
}

template<bool R>
__global__ __launch_bounds__(256) void bn_apply(float* __restrict__ X, long rows,
    const float* __restrict__ sc, const float* __restrict__ sh) {
  const long n4 = rows*64;
  long i = (long)blockIdx.x*256 + threadIdx.x;
  const long st = (long)gridDim.x*256;
  for (; i<n4; i+=st) {
    const int cq = (int)(i & 63);
    float4 v = ((float4*)X)[i];
    const float4 s4 = ((const float4*)sc)[cq];
    const float4 h4 = ((const float4*)sh)[cq];
    v.x = v.x*s4.x + h4.x; v.y = v.y*s4.y + h4.y;
    v.z = v.z*s4.z + h4.z; v.w = v.w*s4.w + h4.w;
    if (R) { v.x=fmaxf(v.x,0.f); v.y=fmaxf(v.y,0.f); v.z=fmaxf(v.z,0.f); v.w=fmaxf(v.w,0.f); }
    ((float4*)X)[i] = v;
  }
}

// ---------------------------------------------------------------- host-side
struct Ctx {
  const unsigned short *WqT,*WkT,*WvT,*WmT,*mw1T,*mw2T,*WfT;
  const float *bm,*l1g,*l1b,*mb1,*mb2,*l2g,*l2b,*b4,*b2,*conv_w,*conv_b;
  const float *h_nodes;
  unsigned short* h_nb;
  unsigned short *bufA,*bufB,*bufC,*bufY;
  float *Zb,*pKV,*KV;
  unsigned short* KVT;
  long CH;
  hipStream_t st;
};

static void run_enc(const Ctx& c, long L, long S,
                    const unsigned short* Asrc, const int* iA,
                    const unsigned short* Bsrc, const int* iB,
                    unsigned short* outB, float* outF, bool fuse,
                    const int* g_src, const int* g_dst, float* lr_e)
{
  hipMemsetAsync(c.KV, 0, 65792*sizeof(float), c.st);
  // phase A: K, V per chunk; accumulate KV = K^T V and Ksum
  for (long s0=0; s0<S; s0+=c.CH) {
    const int cnt = (int)((S-s0 < c.CH) ? (S-s0) : c.CH);
    const int gb = (cnt+63)/64;
    gemm_mf<EPI_ELU1,true><<<gb,256,0,c.st>>>(Bsrc,256,iB,(int)s0, nullptr,0, 256,256,
        c.WkT,256, nullptr,nullptr, nullptr, nullptr,nullptr, nullptr,nullptr,0,
        c.bufA,256,0,cnt);
    gemm_mf<EPI_NONE,true><<<gb,256,0,c.st>>>(Bsrc,256,iB,(int)s0, nullptr,0, 256,256,
        c.WvT,256, nullptr,nullptr, nullptr, nullptr,nullptr, nullptr,nullptr,0,
        c.bufB,256,0,cnt);
    const int P = (cnt+1023)/1024;
    ktv_partial<<<dim3(4,4,P),256,0,c.st>>>(c.bufA,c.bufB,cnt,1024,c.pKV);
    kv_accum<<<257,256,0,c.st>>>(c.pKV,P,c.KV);
  }
  // KVT[b][a] = bf16(KV[a][b])
  wt_build<<<dim3(4,4),256,0,c.st>>>(c.KV,256,256,c.KVT,256,0);
  // phase B
  for (long l0=0; l0<L; l0+=c.CH) {
    const int cnt = (int)((L-l0 < c.CH) ? (L-l0) : c.CH);
    const int gb = (cnt+63)/64;
    gemm_mf<EPI_ELU1,true><<<gb,256,0,c.st>>>(Asrc,256,iA,(int)l0, nullptr,0, 256,256,
        c.WqT,256, nullptr,nullptr, nullptr, nullptr,nullptr, nullptr,nullptr,0,
        c.bufA,256,0,cnt);
    row_dot<<<(cnt+3)/4,256,0,c.st>>>(c.bufA, c.KV+65536, c.Zb, cnt);
    gemm_mf<EPI_DIVZ,true><<<gb,256,0,c.st>>>(c.bufA,256,nullptr,0, nullptr,0, 256,256,
        c.KVT,256, nullptr,nullptr, c.Zb, nullptr,nullptr, nullptr,nullptr,0,
        c.bufB,256,0,cnt);
    gemm_mf<EPI_LN,true><<<gb,256,0,c.st>>>(c.bufB,256,nullptr,0, nullptr,0, 256,256,
        c.WmT,256, c.bm,nullptr, nullptr, c.l1g,c.l1b, nullptr,nullptr,0,
        c.bufC,256,0,cnt);
    gemm_mf<EPI_RELU,true><<<gb,256,0,c.st>>>(Asrc,256,iA,(int)l0, c.bufC,256, 512,256,
        c.mw1T,512, c.mb1,nullptr, nullptr, nullptr,nullptr, nullptr,nullptr,0,
        c.bufY,512,0,cnt);
    gemm_mf<EPI_RELU,true><<<gb,256,0,c.st>>>(Asrc,256,iA,(int)l0, c.bufC,256, 512,256,
        c.mw1T+(long)256*512,512, c.mb1+256,nullptr, nullptr, nullptr,nullptr, nullptr,nullptr,0,
        c.bufY+256,512,0,cnt);
    if (fuse) {
      gemm_mf<EPI_LNRES,true><<<gb,256,0,c.st>>>(c.bufY,512,nullptr,0, nullptr,0, 512,512,
          c.mw2T,512, c.mb2,nullptr, nullptr, c.l2g,c.l2b, c.h_nb,iA,(int)l0,
          c.bufB,256,0,cnt);
      conv_rows<<<cnt,256,0,c.st>>>(c.h_nodes, g_src, g_dst, (int)l0, cnt, c.conv_w, c.conv_b, c.bufA);
      gemm_mf<EPI_NONE,false><<<gb,256,0,c.st>>>(c.bufB,256,nullptr,0, c.bufA,256, 512,256,
          c.WfT,512, c.b4,c.b2, nullptr, nullptr,nullptr, nullptr,nullptr,0,
          lr_e,256,(int)l0,cnt);
    } else if (outF) {
      gemm_mf<EPI_LNRES,false><<<gb,256,0,c.st>>>(c.bufY,512,nullptr,0, nullptr,0, 512,512,
          c.mw2T,512, c.mb2,nullptr, nullptr, c.l2g,c.l2b, c.h_nb,iA,(int)l0,
          outF,256,(int)l0,cnt);
    } else {
      gemm_mf<EPI_LNRES,true><<<gb,256,0,c.st>>>(c.bufY,512,nullptr,0, nullptr,0, 512,512,
          c.mw2T,512, c.mb2,nullptr, nullptr, c.l2g,c.l2b, c.h_nb,iA,(int)l0,
          outB,256,(int)l0,cnt);
    }
  }
}

extern "C" void kernel_launch(void* const* d_in, const int* in_sizes, int n_in,
                              void* d_out, int out_size, void* d_ws, size_t ws_size,
                              hipStream_t stream) {
  const float* h_nodes = (const float*)d_in[0];
  const float* s_u     = (const float*)d_in[1];
  const int*   g_src   = (const int*)d_in[2];
  const int*   g_dst   = (const int*)d_in[3];
  const int*   s_src   = (const int*)d_in[4];
  const int*   s_dst   = (const int*)d_in[5];
  const float* conv_w  = (const float*)d_in[6];
  const float* conv_b  = (const float*)d_in[7];
  const float* W2      = (const float*)d_in[8];
  const float* b2      = (const float*)d_in[9];
  const float* W4      = (const float*)d_in[10];
  const float* b4      = (const float*)d_in[11];
  const float* bn_g    = (const float*)d_in[12];
  const float* bn_b    = (const float*)d_in[13];
  const float* Wq      = (const float*)d_in[14];
  const float* Wk      = (const float*)d_in[15];
  const float* Wv      = (const float*)d_in[16];
  const float* Wm      = (const float*)d_in[17];
  const float* bm      = (const float*)d_in[18];
  const float* l1g     = (const float*)d_in[19];
  const float* l1b     = (const float*)d_in[20];
  const float* mw1     = (const float*)d_in[21];
  const float* mb1     = (const float*)d_in[22];
  const float* mw2     = (const float*)d_in[23];
  const float* mb2     = (const float*)d_in[24];
  const float* l2g     = (const float*)d_in[25];
  const float* l2b     = (const float*)d_in[26];
  (void)in_sizes; (void)n_in; (void)out_size;

  float* lr_e = (float*)d_out;                 // [E,256]
  float* soc  = lr_e + (size_t)En*256;         // [ES,256]

  char* base = (char*)d_ws;
  size_t off = 0;
  auto carve = [&](size_t bytes)->void* {
    void* p = (void*)(base + off);
    off = (off + bytes + 255) & ~(size_t)255;
    return p;
  };
  unsigned short* h_nb = (unsigned short*)carve((size_t)Mn*256*2);
  unsigned short* s_ub = (unsigned short*)carve((size_t)Nn*256*2);
  unsigned short* WqT  = (unsigned short*)carve(65536*2);
  unsigned short* WkT  = (unsigned short*)carve(65536*2);
  unsigned short* WvT  = (unsigned short*)carve(65536*2);
  unsigned short* WmT  = (unsigned short*)carve(65536*2);
  unsigned short* mw1T = (unsigned short*)carve(262144*2);
  unsigned short* mw2T = (unsigned short*)carve(131072*2);
  unsigned short* WfT  = (unsigned short*)carve(131072*2);
  float* KV            = (float*)carve(65792*4);
  unsigned short* KVT  = (unsigned short*)carve(65536*2);
  float* bnpart        = (float*)carve((size_t)512*512*4);
  float* bnscale       = (float*)carve(256*4);
  float* bnshift       = (float*)carve(256*4);

  const size_t remain = ws_size > off ? ws_size - off : 0;
  // per 1024 rows: bufA/B/C (512B/row each) + bufY (1024B/row) + Zb (4B/row); pKV aliases bufY
  long CH = (long)(remain / 2629632) * 1024;
  if (CH > 204800) CH = 204800;
  if (CH < 2048)   CH = 2048;
  unsigned short* bufA = (unsigned short*)carve((size_t)CH*256*2);
  unsigned short* bufB = (unsigned short*)carve((size_t)CH*256*2);
  unsigned short* bufC = (unsigned short*)carve((size_t)CH*256*2);
  unsigned short* bufY = (unsigned short*)carve((size_t)CH*512*2);
  float* Zb            = (float*)carve((size_t)CH*4);
  float* pKV           = (float*)bufY;          // phase-A only; bufY is phase-B only

  // ---- pre-pass: converts + weight transposes
  cvt_b<<<2048,256,0,stream>>>(h_nodes, h_nb, (long)Mn*256);
  cvt_b<<<1024,256,0,stream>>>(s_u, s_ub, (long)Nn*256);
  wt_build<<<dim3(4,4),256,0,stream>>>(Wq, 256,256, WqT, 256, 0);
  wt_build<<<dim3(4,4),256,0,stream>>>(Wk, 256,256, WkT, 256, 0);
  wt_build<<<dim3(4,4),256,0,stream>>>(Wv, 256,256, WvT, 256, 0);
  wt_build<<<dim3(4,4),256,0,stream>>>(Wm, 256,256, WmT, 256, 0);
  wt_build<<<dim3(8,8),256,0,stream>>>(mw1, 512,512, mw1T, 512, 0);
  wt_build<<<dim3(4,8),256,0,stream>>>(mw2, 512,256, mw2T, 512, 0);
  wt_build<<<dim3(4,4),256,0,stream>>>(W4, 256,256, WfT, 512, 0);
  wt_build<<<dim3(4,4),256,0,stream>>>(W2, 256,256, WfT, 512, 256);

  Ctx c;
  c.WqT=WqT; c.WkT=WkT; c.WvT=WvT; c.WmT=WmT; c.mw1T=mw1T; c.mw2T=mw2T; c.WfT=WfT;
  c.bm=bm; c.l1g=l1g; c.l1b=l1b; c.mb1=mb1; c.mb2=mb2; c.l2g=l2g; c.l2b=l2b;
  c.b4=b4; c.b2=b2; c.conv_w=conv_w; c.conv_b=conv_b;
  c.h_nodes=h_nodes; c.h_nb=h_nb;
  c.bufA=bufA; c.bufB=bufB; c.bufC=bufC; c.bufY=bufY;
  c.Zb=Zb; c.pKV=pKV; c.KV=KV; c.KVT=KVT;
  c.CH=CH; c.st=stream;

  // ---- 1. x = enc(h_nodes[:N], s_u) -> h_nb[0:N) (bf16, in place)
  run_enc(c, Nn, Nn, h_nb, nullptr, s_ub, nullptr, h_nb, nullptr, false, nullptr, nullptr, nullptr);
  // ---- 2. edge = enc(h_n[g_src], h_n[g_dst]); fused with conv + W4/W2 -> lr_e (fp32, pre-BN)
  run_enc(c, En, En, h_nb, g_src, h_nb, g_dst, nullptr, nullptr, true, g_src, g_dst, lr_e);
  // ---- 3. social = enc(x[s_src], x[s_dst]) -> soc (fp32, pre-BN)
  run_enc(c, ESn, ESn, h_nb, s_src, h_nb, s_dst, nullptr, soc, false, nullptr, nullptr, nullptr);

  // ---- 4. lr_e = relu(BN(lr_e))
  {
    const int P3 = (En+511)/512;
    bn_stats<<<P3,256,0,stream>>>(lr_e,(long)En,512,bnpart);
    bn_finalize<<<1,256,0,stream>>>(bnpart,P3,(long)En,bn_g,bn_b,bnscale,bnshift);
    bn_apply<true><<<2048,256,0,stream>>>(lr_e,(long)En,bnscale,bnshift);
  }
  // ---- 5. soc = BN(soc)
  {
    const int P4 = (ESn+511)/512;
    bn_stats<<<P4,256,0,stream>>>(soc,(long)ESn,512,bnpart);
    bn_finalize<<<1,256,0,stream>>>(bnpart,P4,(long)ESn,bn_g,bn_b,bnscale,bnshift);
    bn_apply<false><<<2048,256,0,stream>>>(soc,(long)ESn,bnscale,bnshift);
  }
}

// Round 3
// 2982.426 us; speedup vs baseline: 5.2189x; 1.1399x over previous
//
#include <hip/hip_runtime.h>

static constexpr int Mn  = 50000;
static constexpr int Nn  = 20000;
static constexpr int En  = 200000;
static constexpr int ESn = 100000;

typedef short short8v __attribute__((ext_vector_type(8)));
typedef short short4v __attribute__((ext_vector_type(4)));
typedef float f32x4   __attribute__((ext_vector_type(4)));

enum { EPI_NONE=0, EPI_ELU1=1, EPI_RELU=2, EPI_DIVZ=3, EPI_LN=4, EPI_LNRES=5 };

__device__ __forceinline__ float b2f(unsigned short h) {
  unsigned int u = ((unsigned int)h) << 16;
  return __builtin_bit_cast(float, u);
}
__device__ __forceinline__ unsigned short f2b(float f) {
  unsigned int u = __builtin_bit_cast(unsigned int, f);
  u = (u + 0x7FFFu + ((u >> 16) & 1u)) >> 16;
  return (unsigned short)u;
}

// ---------------------------------------------------------------- fp32 -> bf16 flat convert
__global__ __launch_bounds__(256) void cvt_b(const float* __restrict__ s,
                                             unsigned short* __restrict__ d, long n) {
  long g  = (long)blockIdx.x*256 + threadIdx.x;
  long st = (long)gridDim.x*256;
  for (; g*8 < n; g += st) {
    const float4 a = *(const float4*)(s + g*8);
    const float4 b = *(const float4*)(s + g*8 + 4);
    short8v o;
    o[0]=(short)f2b(a.x); o[1]=(short)f2b(a.y); o[2]=(short)f2b(a.z); o[3]=(short)f2b(a.w);
    o[4]=(short)f2b(b.x); o[5]=(short)f2b(b.y); o[6]=(short)f2b(b.z); o[7]=(short)f2b(b.w);
    *(short8v*)(d + g*8) = o;
  }
}

// ---------------------------------------------------------------- W [K][N] fp32 -> WT[n*ldo + koff + k] bf16
__global__ __launch_bounds__(256) void wt_build(const float* __restrict__ W, int K, int N,
    unsigned short* __restrict__ WT, int ldo, int koff) {
  __shared__ unsigned short T[64][72];
  const int t  = threadIdx.x;
  const int n0 = blockIdx.x << 6, k0 = blockIdx.y << 6;
  const int kr = t >> 2, nc = (t & 3) << 4;
#pragma unroll
  for (int j = 0; j < 16; j += 4) {
    float4 v = *(const float4*)(W + (long)(k0+kr)*N + n0 + nc + j);
    T[kr][nc+j+0]=f2b(v.x); T[kr][nc+j+1]=f2b(v.y);
    T[kr][nc+j+2]=f2b(v.z); T[kr][nc+j+3]=f2b(v.w);
  }
  __syncthreads();
  const int nr = t >> 2, kc = (t & 3) << 4;
  unsigned short tmp[16];
#pragma unroll
  for (int j = 0; j < 16; ++j) tmp[j] = T[kc+j][nr];
  unsigned short* o = WT + (long)(n0+nr)*ldo + koff + k0 + kc;
  short8v u0, u1;
#pragma unroll
  for (int j = 0; j < 8; ++j) { u0[j] = (short)tmp[j]; u1[j] = (short)tmp[8+j]; }
  *(short8v*)o       = u0;
  *(short8v*)(o + 8) = u1;
}

// ---------------------------------------------------------------- MFMA GEMM, full-width 256 cols
template<int EPI, bool OBF16>
__global__ __launch_bounds__(256,2) void gemm_mf(
    const unsigned short* __restrict__ A0, int lda0,
    const int* __restrict__ idxA, int aoff,
    const unsigned short* __restrict__ A1, int lda1,
    int K, int K0,
    const unsigned short* __restrict__ WT, int ldwt,
    const float* __restrict__ bias0, const float* __restrict__ bias1,
    const float* __restrict__ Zr,
    const float* __restrict__ lng, const float* __restrict__ lnb,
    const unsigned short* RESB, const int* __restrict__ idxR, int roff,
    void* Cv, int ldc, int dc0, int nrows)
{
  __shared__ short As[64*64];
  __shared__ short Bs[256*64];
  __shared__ float2 red[64][5];

  const int t    = threadIdx.x;
  const int w    = t >> 6;
  const int lane = t & 63;
  const int q    = lane >> 4;
  const int hw   = lane & 15;
  const int r0   = blockIdx.x << 6;

  const int arow = t >> 2;
  const int akc  = (t & 3) << 1;
  const int alr  = r0 + arow;
  const bool avalid = alr < nrows;
  long arid = 0;
  if (avalid) arid = idxA ? (long)idxA[aoff + alr] : (long)(aoff + alr);

  f32x4 acc[4][4];
#pragma unroll
  for (int m=0;m<4;++m)
#pragma unroll
    for (int n=0;n<4;++n) acc[m][n] = (f32x4){0.f,0.f,0.f,0.f};

  for (int kb = 0; kb < K; kb += 64) {
    short8v av0 = {0,0,0,0,0,0,0,0}, av1 = {0,0,0,0,0,0,0,0};
    if (avalid) {
      const unsigned short* ap;
      if (kb < K0) ap = A0 + arid*(long)lda0 + kb + ((t&3)<<4);
      else         ap = A1 + (long)alr*lda1 + (kb - K0) + ((t&3)<<4);
      av0 = *(const short8v*)ap;
      av1 = *(const short8v*)(ap + 8);
    }
    short8v bv[8];
    const unsigned short* bp = WT + (long)t*ldwt + kb;
#pragma unroll
    for (int j=0;j<8;++j) bv[j] = *(const short8v*)(bp + j*8);

    __syncthreads();
    *(short8v*)&As[arow*64 + (((akc  ) ^ (arow&7))<<3)] = av0;
    *(short8v*)&As[arow*64 + (((akc+1) ^ (arow&7))<<3)] = av1;
#pragma unroll
    for (int j=0;j<8;++j)
      *(short8v*)&Bs[t*64 + ((j ^ (t&7))<<3)] = bv[j];
    __syncthreads();

#pragma unroll
    for (int kk=0;kk<2;++kk) {
      const int kc = (kk<<2) + q;
      short8v af[4], bf[4];
#pragma unroll
      for (int m=0;m<4;++m)
        af[m] = *(const short8v*)&As[(m*16+hw)*64 + ((kc ^ (hw&7))<<3)];
#pragma unroll
      for (int n=0;n<4;++n)
        bf[n] = *(const short8v*)&Bs[(w*64+n*16+hw)*64 + ((kc ^ (hw&7))<<3)];
#pragma unroll
      for (int m=0;m<4;++m)
#pragma unroll
        for (int n=0;n<4;++n)
          acc[m][n] = __builtin_amdgcn_mfma_f32_16x16x32_bf16(af[m], bf[n], acc[m][n], 0,0,0);
    }
  }

  // ---------------- epilogue ----------------
  float bia[4] = {0.f,0.f,0.f,0.f};
#pragma unroll
  for (int n=0;n<4;++n) {
    const int c = w*64 + n*16 + hw;
    if (bias0) bia[n] += bias0[c];
    if (bias1) bia[n] += bias1[c];
  }
#pragma unroll
  for (int m=0;m<4;++m)
#pragma unroll
    for (int n=0;n<4;++n)
#pragma unroll
      for (int i=0;i<4;++i) acc[m][n][i] += bia[n];

  if constexpr (EPI == EPI_ELU1) {
#pragma unroll
    for (int m=0;m<4;++m)
#pragma unroll
      for (int n=0;n<4;++n)
#pragma unroll
        for (int i=0;i<4;++i) {
          float v = acc[m][n][i];
          acc[m][n][i] = v > 0.f ? v + 1.f : __expf(v);
        }
  }
  if constexpr (EPI == EPI_RELU) {
#pragma unroll
    for (int m=0;m<4;++m)
#pragma unroll
      for (int n=0;n<4;++n)
#pragma unroll
        for (int i=0;i<4;++i) acc[m][n][i] = fmaxf(acc[m][n][i], 0.f);
  }
  if constexpr (EPI == EPI_DIVZ) {
#pragma unroll
    for (int m=0;m<4;++m) {
      f32x4 z = *(const f32x4*)(Zr + r0 + m*16 + q*4);
#pragma unroll
      for (int i=0;i<4;++i) {
        const float iz = 1.f / z[i];
#pragma unroll
        for (int n=0;n<4;++n) acc[m][n][i] *= iz;
      }
    }
  }

  float mu[4][4], rsg[4][4];
  float lg[4], lb[4];
  if constexpr (EPI == EPI_LN || EPI == EPI_LNRES) {
#pragma unroll
    for (int n=0;n<4;++n) {
      const int c = w*64 + n*16 + hw;
      lg[n] = lng[c]; lb[n] = lnb[c];
    }
    float s1[4][4], s2[4][4];
#pragma unroll
    for (int m=0;m<4;++m)
#pragma unroll
      for (int i=0;i<4;++i) {
        float s = 0.f, sq = 0.f;
#pragma unroll
        for (int n=0;n<4;++n) { const float v = acc[m][n][i]; s += v; sq += v*v; }
        s1[m][i] = s; s2[m][i] = sq;
      }
#pragma unroll
    for (int off=1; off<16; off<<=1)
#pragma unroll
      for (int m=0;m<4;++m)
#pragma unroll
        for (int i=0;i<4;++i) {
          s1[m][i] += __shfl_xor(s1[m][i], off);
          s2[m][i] += __shfl_xor(s2[m][i], off);
        }
    if (hw == 0) {
#pragma unroll
      for (int m=0;m<4;++m)
#pragma unroll
        for (int i=0;i<4;++i)
          red[m*16 + q*4 + i][w] = make_float2(s1[m][i], s2[m][i]);
    }
    __syncthreads();
#pragma unroll
    for (int m=0;m<4;++m)
#pragma unroll
      for (int i=0;i<4;++i) {
        float ts = 0.f, tq = 0.f;
#pragma unroll
        for (int ww=0;ww<4;++ww) {
          const float2 v = red[m*16 + q*4 + i][ww];
          ts += v.x; tq += v.y;
        }
        const float mmu = ts * (1.f/256.f);
        float var = tq * (1.f/256.f) - mmu*mmu;
        var = var > 0.f ? var : 0.f;
        mu[m][i]  = mmu;
        rsg[m][i] = rsqrtf(var + 1e-5f);
      }
  }

#pragma unroll
  for (int m=0;m<4;++m) {
#pragma unroll
    for (int i=0;i<4;++i) {
      const int rr = m*16 + q*4 + i;
      const int lr = r0 + rr;
      if (lr >= nrows) continue;
      long rid = 0;
      if constexpr (EPI == EPI_LNRES)
        rid = idxR ? (long)idxR[roff + lr] : (long)(roff + lr);
#pragma unroll
      for (int n=0;n<4;++n) {
        const int c = w*64 + n*16 + hw;
        float v = acc[m][n][i];
        if constexpr (EPI == EPI_LN || EPI == EPI_LNRES)
          v = (v - mu[m][i]) * rsg[m][i] * lg[n] + lb[n];
        if constexpr (EPI == EPI_LNRES)
          v += b2f(RESB[rid*256 + c]);
        const long coff = (long)(dc0 + lr)*ldc + c;
        if constexpr (OBF16) ((unsigned short*)Cv)[coff] = f2b(v);
        else                 ((float*)Cv)[coff] = v;
      }
    }
  }
}

// ---------------------------------------------------------------- K^T V via MFMA, split-K over rows
// Output partials: pKV[p][a*256+b] (128x128 tile per block), pKV[p][65536+a] = colsum K
// Grid: (2, 2, P); block 256 thr = 4 waves (2x2), each wave 64x64 output.
__global__ __launch_bounds__(256,2) void ktv_mfma(
    const unsigned short* __restrict__ Kb, const unsigned short* __restrict__ Vb,
    int rows, int rpp, float* __restrict__ pKV)
{
  __shared__ short As[128*64];   // As[a][r] = K[r][a0+a], r swizzled
  __shared__ short Bs[128*64];   // Bs[b][r] = V[r][b0+b]
  const int t  = threadIdx.x;
  const int w  = t >> 6;
  const int l  = t & 63;
  const int q  = l >> 4;
  const int hw = l & 15;
  const int wa = w >> 1, wb = w & 1;
  const int a0 = blockIdx.x << 7;
  const int b0 = blockIdx.y << 7;
  const int p  = blockIdx.z;
  const int rbeg = p * rpp;
  const int rend = min(rows, rbeg + rpp);

  f32x4 acc[4][4];
#pragma unroll
  for (int m=0;m<4;++m)
#pragma unroll
    for (int n=0;n<4;++n) acc[m][n] = (f32x4){0.f,0.f,0.f,0.f};
  float ksum = 0.f;   // threads t<128 (when blockIdx.y==0): colsum of K for a = a0 + t

  for (int r0 = rbeg; r0 < rend; r0 += 64) {
    const int gr = r0 + l;               // lane = row
    const bool valid = gr < rend;
    short8v kf[4], vf[4];
#pragma unroll
    for (int j=0;j<4;++j) {
      if (valid) {
        kf[j] = *(const short8v*)(Kb + (long)gr*256 + a0 + w*32 + j*8);
        vf[j] = *(const short8v*)(Vb + (long)gr*256 + b0 + w*32 + j*8);
      } else {
        kf[j] = (short8v){0,0,0,0,0,0,0,0};
        vf[j] = (short8v){0,0,0,0,0,0,0,0};
      }
    }
    __syncthreads();
#pragma unroll
    for (int j=0;j<4;++j)
#pragma unroll
      for (int e=0;e<8;++e) {
        const int a = w*32 + j*8 + e;            // a&7 == e
        As[a*64 + (l ^ (e<<3))] = kf[j][e];
        Bs[a*64 + (l ^ (e<<3))] = vf[j][e];
      }
    __syncthreads();

#pragma unroll
    for (int kk=0;kk<2;++kk) {
      const int kc = (kk<<2) + q;
      short8v af[4], bf[4];
#pragma unroll
      for (int m=0;m<4;++m)
        af[m] = *(const short8v*)&As[(wa*64+m*16+hw)*64 + ((kc ^ (hw&7))<<3)];
#pragma unroll
      for (int n=0;n<4;++n)
        bf[n] = *(const short8v*)&Bs[(wb*64+n*16+hw)*64 + ((kc ^ (hw&7))<<3)];
#pragma unroll
      for (int m=0;m<4;++m)
#pragma unroll
        for (int n=0;n<4;++n)
          acc[m][n] = __builtin_amdgcn_mfma_f32_16x16x32_bf16(af[m], bf[n], acc[m][n], 0,0,0);
    }

    if (blockIdx.y == 0 && t < 128) {
#pragma unroll
      for (int kc=0;kc<8;++kc) {
        short8v v = *(const short8v*)&As[t*64 + ((kc ^ (t&7))<<3)];
#pragma unroll
        for (int e=0;e<8;++e) ksum += b2f((unsigned short)v[e]);
      }
    }
  }

  const long base = (long)p * 65792;
#pragma unroll
  for (int m=0;m<4;++m)
#pragma unroll
    for (int i=0;i<4;++i) {
      const int a = a0 + wa*64 + m*16 + q*4 + i;
#pragma unroll
      for (int n=0;n<4;++n) {
        const int b = b0 + wb*64 + n*16 + hw;
        pKV[base + (long)a*256 + b] = acc[m][n][i];
      }
    }
  if (blockIdx.y == 0 && t < 128) pKV[base + 65536 + a0 + t] = ksum;
}

__global__ __launch_bounds__(256) void kv_accum(const float* __restrict__ pKV, int P,
                                                float* __restrict__ KV) {
  const int i = blockIdx.x*256 + threadIdx.x;
  if (i >= 65792) return;
  float s = 0.f;
  for (int p=0;p<P;++p) s += pKV[(long)p*65792 + i];
  KV[i] += s;
}

// Z[r] = Q[r,:] . Ksum + 1e-6  (one wave per row, Q bf16)
__global__ __launch_bounds__(256) void row_dot(const unsigned short* __restrict__ Q,
    const float* __restrict__ Ksum, float* __restrict__ Z, int rows) {
  const long gid = (long)blockIdx.x*256 + threadIdx.x;
  const int row = (int)(gid >> 6);
  const int lane = (int)(gid & 63);
  if (row >= rows) return;
  short4v q4 = *(const short4v*)(Q + (long)row*256 + lane*4);
  const float4 k = *(const float4*)(Ksum + lane*4);
  float s = b2f((unsigned short)q4[0])*k.x + b2f((unsigned short)q4[1])*k.y
          + b2f((unsigned short)q4[2])*k.z + b2f((unsigned short)q4[3])*k.w;
#pragma unroll
  for (int off=32; off; off>>=1) s += __shfl_xor(s, off);
  if (lane==0) Z[row] = s + 1e-6f;
}

// Conv1d(2->1, k=3, pad=1) over gathered src/dst rows of ORIGINAL h_nodes -> bf16
__global__ __launch_bounds__(256) void conv_rows(const float* __restrict__ h,
    const int* __restrict__ gs, const int* __restrict__ gd, int gr0, int rows,
    const float* __restrict__ cw, const float* __restrict__ cb,
    unsigned short* __restrict__ Cc) {
  const int r = blockIdx.x;
  if (r >= rows) return;
  const int d = threadIdx.x;
  const float* sr = h + (long)gs[gr0+r]*256;
  const float* dr = h + (long)gd[gr0+r]*256;
  const float sm = d>0   ? sr[d-1] : 0.f;
  const float sp = d<255 ? sr[d+1] : 0.f;
  const float dm = d>0   ? dr[d-1] : 0.f;
  const float dp = d<255 ? dr[d+1] : 0.f;
  Cc[(long)r*256 + d] = f2b(cb[0] + cw[0]*sm + cw[1]*sr[d] + cw[2]*sp
                                  + cw[3]*dm + cw[4]*dr[d] + cw[5]*dp);
}

// ---------------------------------------------------------------- BatchNorm (train), fp32 in place
__global__ __launch_bounds__(256) void bn_stats(const float* __restrict__ X, long rows,
    int rpb, float* __restrict__ part) {
  const int p = blockIdx.x;
  const int c = threadIdx.x;
  long r0 = (long)p*rpb;
  long r1 = r0 + rpb; if (r1 > rows) r1 = rows;
  float s=0.f, s2=0.f;
  for (long r=r0; r<r1; ++r) { const float v = X[r*256 + c]; s += v; s2 += v*v; }
  part[(long)p*512 + c] = s;
  part[(long)p*512 + 256 + c] = s2;
}

__global__ __launch_bounds__(256) void bn_finalize(const float* __restrict__ part, int P,
    long rows, const float* __restrict__ g, const float* __restrict__ b,
    float* __restrict__ scale, float* __restrict__ shift) {
  const int c = threadIdx.x;
  float s=0.f, s2=0.f;
  for (int p=0;p<P;++p) { s += part[(long)p*512 + c]; s2 += part[(long)p*512 + 256 + c]; }
  const float inv = 1.f/(float)rows;
  const float mu = s*inv;
  float var = s2*inv - mu*mu;
  var = var > 0.f ? var : 0.f;
  const float rs = rsqrtf(var + 1e-5f);
  scale[c] = g[c]*rs;
  shift[c] = b[c] - mu*g[c]*rs;
}

template<bool R>
__global__ __launch_bounds__(256) void bn_apply(float* __restrict__ X, long rows,
    const float* __restrict__ sc, const float* __restrict__ sh) {
  const long n4 = rows*64;
  long i = (long)blockIdx.x*256 + threadIdx.x;
  const long st = (long)gridDim.x*256;
  for (; i<n4; i+=st) {
    const int cq = (int)(i & 63);
    float4 v = ((float4*)X)[i];
    const float4 s4 = ((const float4*)sc)[cq];
    const float4 h4 = ((const float4*)sh)[cq];
    v.x = v.x*s4.x + h4.x; v.y = v.y*s4.y + h4.y;
    v.z = v.z*s4.z + h4.z; v.w = v.w*s4.w + h4.w;
    if (R) { v.x=fmaxf(v.x,0.f); v.y=fmaxf(v.y,0.f); v.z=fmaxf(v.z,0.f); v.w=fmaxf(v.w,0.f); }
    ((float4*)X)[i] = v;
  }
}

// ---------------------------------------------------------------- host-side
struct Ctx {
  const unsigned short *WqT,*WkT,*WvT,*WmT,*mw1T,*mw2T,*WfT;
  const float *bm,*l1g,*l1b,*mb1,*mb2,*l2g,*l2b,*b4,*b2,*conv_w,*conv_b;
  const float *h_nodes;
  unsigned short* h_nb;
  unsigned short *bufA,*bufB,*bufC,*bufY;
  float *Zb,*pKV,*KV;
  unsigned short* KVT;
  long CH;
  hipStream_t st;
};

static void run_enc(const Ctx& c, long L, long S,
                    const unsigned short* Asrc, const int* iA,
                    const unsigned short* Bsrc, const int* iB,
                    unsigned short* outB, float* outF, bool fuse,
                    const int* g_src, const int* g_dst, float* lr_e)
{
  hipMemsetAsync(c.KV, 0, 65792*sizeof(float), c.st);
  // phase A: K, V per chunk; accumulate KV = K^T V and Ksum
  for (long s0=0; s0<S; s0+=c.CH) {
    const int cnt = (int)((S-s0 < c.CH) ? (S-s0) : c.CH);
    const int gb = (cnt+63)/64;
    gemm_mf<EPI_ELU1,true><<<gb,256,0,c.st>>>(Bsrc,256,iB,(int)s0, nullptr,0, 256,256,
        c.WkT,256, nullptr,nullptr, nullptr, nullptr,nullptr, nullptr,nullptr,0,
        c.bufA,256,0,cnt);
    gemm_mf<EPI_NONE,true><<<gb,256,0,c.st>>>(Bsrc,256,iB,(int)s0, nullptr,0, 256,256,
        c.WvT,256, nullptr,nullptr, nullptr, nullptr,nullptr, nullptr,nullptr,0,
        c.bufB,256,0,cnt);
    const int P = (cnt+2047)/2048;
    ktv_mfma<<<dim3(2,2,P),256,0,c.st>>>(c.bufA,c.bufB,cnt,2048,c.pKV);
    kv_accum<<<257,256,0,c.st>>>(c.pKV,P,c.KV);
  }
  // KVT[b][a] = bf16(KV[a][b])
  wt_build<<<dim3(4,4),256,0,c.st>>>(c.KV,256,256,c.KVT,256,0);
  // phase B
  for (long l0=0; l0<L; l0+=c.CH) {
    const int cnt = (int)((L-l0 < c.CH) ? (L-l0) : c.CH);
    const int gb = (cnt+63)/64;
    gemm_mf<EPI_ELU1,true><<<gb,256,0,c.st>>>(Asrc,256,iA,(int)l0, nullptr,0, 256,256,
        c.WqT,256, nullptr,nullptr, nullptr, nullptr,nullptr, nullptr,nullptr,0,
        c.bufA,256,0,cnt);
    row_dot<<<(cnt+3)/4,256,0,c.st>>>(c.bufA, c.KV+65536, c.Zb, cnt);
    gemm_mf<EPI_DIVZ,true><<<gb,256,0,c.st>>>(c.bufA,256,nullptr,0, nullptr,0, 256,256,
        c.KVT,256, nullptr,nullptr, c.Zb, nullptr,nullptr, nullptr,nullptr,0,
        c.bufB,256,0,cnt);
    gemm_mf<EPI_LN,true><<<gb,256,0,c.st>>>(c.bufB,256,nullptr,0, nullptr,0, 256,256,
        c.WmT,256, c.bm,nullptr, nullptr, c.l1g,c.l1b, nullptr,nullptr,0,
        c.bufC,256,0,cnt);
    gemm_mf<EPI_RELU,true><<<gb,256,0,c.st>>>(Asrc,256,iA,(int)l0, c.bufC,256, 512,256,
        c.mw1T,512, c.mb1,nullptr, nullptr, nullptr,nullptr, nullptr,nullptr,0,
        c.bufY,512,0,cnt);
    gemm_mf<EPI_RELU,true><<<gb,256,0,c.st>>>(Asrc,256,iA,(int)l0, c.bufC,256, 512,256,
        c.mw1T+(long)256*512,512, c.mb1+256,nullptr, nullptr, nullptr,nullptr, nullptr,nullptr,0,
        c.bufY+256,512,0,cnt);
    if (fuse) {
      gemm_mf<EPI_LNRES,true><<<gb,256,0,c.st>>>(c.bufY,512,nullptr,0, nullptr,0, 512,512,
          c.mw2T,512, c.mb2,nullptr, nullptr, c.l2g,c.l2b, c.h_nb,iA,(int)l0,
          c.bufB,256,0,cnt);
      conv_rows<<<cnt,256,0,c.st>>>(c.h_nodes, g_src, g_dst, (int)l0, cnt, c.conv_w, c.conv_b, c.bufA);
      gemm_mf<EPI_NONE,false><<<gb,256,0,c.st>>>(c.bufB,256,nullptr,0, c.bufA,256, 512,256,
          c.WfT,512, c.b4,c.b2, nullptr, nullptr,nullptr, nullptr,nullptr,0,
          lr_e,256,(int)l0,cnt);
    } else if (outF) {
      gemm_mf<EPI_LNRES,false><<<gb,256,0,c.st>>>(c.bufY,512,nullptr,0, nullptr,0, 512,512,
          c.mw2T,512, c.mb2,nullptr, nullptr, c.l2g,c.l2b, c.h_nb,iA,(int)l0,
          outF,256,(int)l0,cnt);
    } else {
      gemm_mf<EPI_LNRES,true><<<gb,256,0,c.st>>>(c.bufY,512,nullptr,0, nullptr,0, 512,512,
          c.mw2T,512, c.mb2,nullptr, nullptr, c.l2g,c.l2b, c.h_nb,iA,(int)l0,
          outB,256,(int)l0,cnt);
    }
  }
}

extern "C" void kernel_launch(void* const* d_in, const int* in_sizes, int n_in,
                              void* d_out, int out_size, void* d_ws, size_t ws_size,
                              hipStream_t stream) {
  const float* h_nodes = (const float*)d_in[0];
  const float* s_u     = (const float*)d_in[1];
  const int*   g_src   = (const int*)d_in[2];
  const int*   g_dst   = (const int*)d_in[3];
  const int*   s_src   = (const int*)d_in[4];
  const int*   s_dst   = (const int*)d_in[5];
  const float* conv_w  = (const float*)d_in[6];
  const float* conv_b  = (const float*)d_in[7];
  const float* W2      = (const float*)d_in[8];
  const float* b2      = (const float*)d_in[9];
  const float* W4      = (const float*)d_in[10];
  const float* b4      = (const float*)d_in[11];
  const float* bn_g    = (const float*)d_in[12];
  const float* bn_b    = (const float*)d_in[13];
  const float* Wq      = (const float*)d_in[14];
  const float* Wk      = (const float*)d_in[15];
  const float* Wv      = (const float*)d_in[16];
  const float* Wm      = (const float*)d_in[17];
  const float* bm      = (const float*)d_in[18];
  const float* l1g     = (const float*)d_in[19];
  const float* l1b     = (const float*)d_in[20];
  const float* mw1     = (const float*)d_in[21];
  const float* mb1     = (const float*)d_in[22];
  const float* mw2     = (const float*)d_in[23];
  const float* mb2     = (const float*)d_in[24];
  const float* l2g     = (const float*)d_in[25];
  const float* l2b     = (const float*)d_in[26];
  (void)in_sizes; (void)n_in; (void)out_size;

  float* lr_e = (float*)d_out;                 // [E,256]
  float* soc  = lr_e + (size_t)En*256;         // [ES,256]

  char* base = (char*)d_ws;
  size_t off = 0;
  auto carve = [&](size_t bytes)->void* {
    void* p = (void*)(base + off);
    off = (off + bytes + 255) & ~(size_t)255;
    return p;
  };
  unsigned short* h_nb = (unsigned short*)carve((size_t)Mn*256*2);
  unsigned short* s_ub = (unsigned short*)carve((size_t)Nn*256*2);
  unsigned short* WqT  = (unsigned short*)carve(65536*2);
  unsigned short* WkT  = (unsigned short*)carve(65536*2);
  unsigned short* WvT  = (unsigned short*)carve(65536*2);
  unsigned short* WmT  = (unsigned short*)carve(65536*2);
  unsigned short* mw1T = (unsigned short*)carve(262144*2);
  unsigned short* mw2T = (unsigned short*)carve(131072*2);
  unsigned short* WfT  = (unsigned short*)carve(131072*2);
  float* KV            = (float*)carve(65792*4);
  unsigned short* KVT  = (unsigned short*)carve(65536*2);
  float* bnpart        = (float*)carve((size_t)512*512*4);
  float* bnscale       = (float*)carve(256*4);
  float* bnshift       = (float*)carve(256*4);

  const size_t remain = ws_size > off ? ws_size - off : 0;
  // per 1024 rows: bufA/B/C (512B/row each) + bufY (1024B/row) + Zb (4B/row); pKV aliases bufY
  long CH = (long)(remain / 2629632) * 1024;
  if (CH > 204800) CH = 204800;
  if (CH < 2048)   CH = 2048;
  unsigned short* bufA = (unsigned short*)carve((size_t)CH*256*2);
  unsigned short* bufB = (unsigned short*)carve((size_t)CH*256*2);
  unsigned short* bufC = (unsigned short*)carve((size_t)CH*256*2);
  unsigned short* bufY = (unsigned short*)carve((size_t)CH*512*2);
  float* Zb            = (float*)carve((size_t)CH*4);
  float* pKV           = (float*)bufY;          // phase-A only; bufY is phase-B only

  // ---- pre-pass: converts + weight transposes
  cvt_b<<<2048,256,0,stream>>>(h_nodes, h_nb, (long)Mn*256);
  cvt_b<<<1024,256,0,stream>>>(s_u, s_ub, (long)Nn*256);
  wt_build<<<dim3(4,4),256,0,stream>>>(Wq, 256,256, WqT, 256, 0);
  wt_build<<<dim3(4,4),256,0,stream>>>(Wk, 256,256, WkT, 256, 0);
  wt_build<<<dim3(4,4),256,0,stream>>>(Wv, 256,256, WvT, 256, 0);
  wt_build<<<dim3(4,4),256,0,stream>>>(Wm, 256,256, WmT, 256, 0);
  wt_build<<<dim3(8,8),256,0,stream>>>(mw1, 512,512, mw1T, 512, 0);
  wt_build<<<dim3(4,8),256,0,stream>>>(mw2, 512,256, mw2T, 512, 0);
  wt_build<<<dim3(4,4),256,0,stream>>>(W4, 256,256, WfT, 512, 0);
  wt_build<<<dim3(4,4),256,0,stream>>>(W2, 256,256, WfT, 512, 256);

  Ctx c;
  c.WqT=WqT; c.WkT=WkT; c.WvT=WvT; c.WmT=WmT; c.mw1T=mw1T; c.mw2T=mw2T; c.WfT=WfT;
  c.bm=bm; c.l1g=l1g; c.l1b=l1b; c.mb1=mb1; c.mb2=mb2; c.l2g=l2g; c.l2b=l2b;
  c.b4=b4; c.b2=b2; c.conv_w=conv_w; c.conv_b=conv_b;
  c.h_nodes=h_nodes; c.h_nb=h_nb;
  c.bufA=bufA; c.bufB=bufB; c.bufC=bufC; c.bufY=bufY;
  c.Zb=Zb; c.pKV=pKV; c.KV=KV; c.KVT=KVT;
  c.CH=CH; c.st=stream;

  // ---- 1. x = enc(h_nodes[:N], s_u) -> h_nb[0:N) (bf16, in place)
  run_enc(c, Nn, Nn, h_nb, nullptr, s_ub, nullptr, h_nb, nullptr, false, nullptr, nullptr, nullptr);
  // ---- 2. edge = enc(h_n[g_src], h_n[g_dst]); fused with conv + W4/W2 -> lr_e (fp32, pre-BN)
  run_enc(c, En, En, h_nb, g_src, h_nb, g_dst, nullptr, nullptr, true, g_src, g_dst, lr_e);
  // ---- 3. social = enc(x[s_src], x[s_dst]) -> soc (fp32, pre-BN)
  run_enc(c, ESn, ESn, h_nb, s_src, h_nb, s_dst, nullptr, soc, false, nullptr, nullptr, nullptr);

  // ---- 4. lr_e = relu(BN(lr_e))
  {
    const int P3 = (En+511)/512;
    bn_stats<<<P3,256,0,stream>>>(lr_e,(long)En,512,bnpart);
    bn_finalize<<<1,256,0,stream>>>(bnpart,P3,(long)En,bn_g,bn_b,bnscale,bnshift);
    bn_apply<true><<<2048,256,0,stream>>>(lr_e,(long)En,bnscale,bnshift);
  }
  // ---- 5. soc = BN(soc)
  {
    const int P4 = (ESn+511)/512;
    bn_stats<<<P4,256,0,stream>>>(soc,(long)ESn,512,bnpart);
    bn_finalize<<<1,256,0,stream>>>(bnpart,P4,(long)ESn,bn_g,bn_b,bnscale,bnshift);
    bn_apply<false><<<2048,256,0,stream>>>(soc,(long)ESn,bnscale,bnshift);
  }
}

// Round 4
// 2975.739 us; speedup vs baseline: 5.2307x; 1.0022x over previous
//
#include <hip/hip_runtime.h>

static constexpr int Mn  = 50000;
static constexpr int Nn  = 20000;
static constexpr int En  = 200000;
static constexpr int ESn = 100000;

typedef short short8v __attribute__((ext_vector_type(8)));
typedef short short4v __attribute__((ext_vector_type(4)));
typedef float f32x4   __attribute__((ext_vector_type(4)));

enum { EPI_NONE=0, EPI_ELU1=1, EPI_RELU=2, EPI_DIVZ=3, EPI_LN=4, EPI_LNRES=5 };

__device__ __forceinline__ float b2f(unsigned short h) {
  unsigned int u = ((unsigned int)h) << 16;
  return __builtin_bit_cast(float, u);
}
__device__ __forceinline__ unsigned short f2b(float f) {
  unsigned int u = __builtin_bit_cast(unsigned int, f);
  u = (u + 0x7FFFu + ((u >> 16) & 1u)) >> 16;
  return (unsigned short)u;
}
// async global->LDS, 16B per lane; LDS dest must be wave-uniform base (+lane*16)
__device__ __forceinline__ void gld16(const void* g, void* l) {
  __builtin_amdgcn_global_load_lds(
      (const __attribute__((address_space(1))) void*)g,
      (__attribute__((address_space(3))) void*)l, 16, 0, 0);
}

// ---------------------------------------------------------------- fp32 -> bf16 flat convert
__global__ __launch_bounds__(256) void cvt_b(const float* __restrict__ s,
                                             unsigned short* __restrict__ d, long n) {
  long g  = (long)blockIdx.x*256 + threadIdx.x;
  long st = (long)gridDim.x*256;
  for (; g*8 < n; g += st) {
    const float4 a = *(const float4*)(s + g*8);
    const float4 b = *(const float4*)(s + g*8 + 4);
    short8v o;
    o[0]=(short)f2b(a.x); o[1]=(short)f2b(a.y); o[2]=(short)f2b(a.z); o[3]=(short)f2b(a.w);
    o[4]=(short)f2b(b.x); o[5]=(short)f2b(b.y); o[6]=(short)f2b(b.z); o[7]=(short)f2b(b.w);
    *(short8v*)(d + g*8) = o;
  }
}

// ---------------------------------------------------------------- W [K][N] fp32 -> WT[n*ldo + koff + k] bf16
__global__ __launch_bounds__(256) void wt_build(const float* __restrict__ W, int K, int N,
    unsigned short* __restrict__ WT, int ldo, int koff) {
  __shared__ unsigned short T[64][72];
  const int t  = threadIdx.x;
  const int n0 = blockIdx.x << 6, k0 = blockIdx.y << 6;
  const int kr = t >> 2, nc = (t & 3) << 4;
#pragma unroll
  for (int j = 0; j < 16; j += 4) {
    float4 v = *(const float4*)(W + (long)(k0+kr)*N + n0 + nc + j);
    T[kr][nc+j+0]=f2b(v.x); T[kr][nc+j+1]=f2b(v.y);
    T[kr][nc+j+2]=f2b(v.z); T[kr][nc+j+3]=f2b(v.w);
  }
  __syncthreads();
  const int nr = t >> 2, kc = (t & 3) << 4;
  unsigned short tmp[16];
#pragma unroll
  for (int j = 0; j < 16; ++j) tmp[j] = T[kc+j][nr];
  unsigned short* o = WT + (long)(n0+nr)*ldo + koff + k0 + kc;
  short8v u0, u1;
#pragma unroll
  for (int j = 0; j < 8; ++j) { u0[j] = (short)tmp[j]; u1[j] = (short)tmp[8+j]; }
  *(short8v*)o       = u0;
  *(short8v*)(o + 8) = u1;
}

// ---------------------------------------------------------------- MFMA GEMM, 128 rows x 256 cols per block
// 512 thr = 8 waves (2 row-groups x 4 col-groups), each wave 64x64.
// Staging via global_load_lds with pre-swizzled global source columns; LDS linear dest.
template<int EPI, bool OBF16>
__global__ __launch_bounds__(512,4) void gemm_mf(
    const unsigned short* __restrict__ A0, int lda0,
    const int* __restrict__ idxA, int aoff,
    const unsigned short* __restrict__ A1, int lda1,
    int K, int K0,
    const unsigned short* __restrict__ WT, int ldwt,
    const float* __restrict__ bias0, const float* __restrict__ bias1,
    const float* __restrict__ Zr,
    const float* __restrict__ lng, const float* __restrict__ lnb,
    const unsigned short* RESB, const int* __restrict__ idxR, int roff,
    void* Cv, int ldc, int dc0, int nrows)
{
  __shared__ short As[128*64];   // As[r][s], s = kc ^ (r&7), 16B chunks
  __shared__ short Bs[256*64];
  __shared__ float2 red[128][4];

  const int t  = threadIdx.x;
  const int w  = t >> 6;        // wave 0..7
  const int l  = t & 63;
  const int q  = l >> 4;
  const int hw = l & 15;
  const int wr = w >> 2;        // row group 0..1
  const int wc = w & 3;         // col group 0..3
  const int r0 = blockIdx.x << 7;

  // staging lane roles: row-in-chunk sr, swizzle slot sc; global col chunk = sc ^ sr
  const int sr   = l >> 3;
  const int sc   = l & 7;
  const int gcol = ((sc ^ sr) << 3);    // element offset within the 64-wide k-slab

  const unsigned short* apA[2];
  const unsigned short* apB[2];
#pragma unroll
  for (int j=0;j<2;++j) {
    int lr = r0 + j*64 + w*8 + sr;
    int lrc = lr < nrows ? lr : (nrows-1);
    long rid = idxA ? (long)idxA[aoff + lrc] : (long)(aoff + lrc);
    apA[j] = A0 + rid*(long)lda0 + gcol;
    apB[j] = A1 ? (A1 + (long)lrc*lda1 + gcol) : apA[j];
  }
  const unsigned short* bp[4];
#pragma unroll
  for (int j=0;j<4;++j)
    bp[j] = WT + (long)(j*64 + w*8 + sr)*ldwt + gcol;

  f32x4 acc[4][4];
#pragma unroll
  for (int m=0;m<4;++m)
#pragma unroll
    for (int n=0;n<4;++n) acc[m][n] = (f32x4){0.f,0.f,0.f,0.f};

  for (int kb = 0; kb < K; kb += 64) {
#pragma unroll
    for (int j=0;j<2;++j) {
      const unsigned short* src = (kb < K0) ? (apA[j] + kb) : (apB[j] + (kb - K0));
      gld16(src, &As[(j*64 + w*8)*64]);
    }
#pragma unroll
    for (int j=0;j<4;++j)
      gld16(bp[j] + kb, &Bs[(j*64 + w*8)*64]);
    __syncthreads();           // vmcnt(0) drain + barrier

#pragma unroll
    for (int kk=0;kk<2;++kk) {
      const int kc = (kk<<2) + q;
      short8v af[4], bf[4];
#pragma unroll
      for (int m=0;m<4;++m)
        af[m] = *(const short8v*)&As[(wr*64 + m*16 + hw)*64 + ((kc ^ (hw&7))<<3)];
#pragma unroll
      for (int n=0;n<4;++n)
        bf[n] = *(const short8v*)&Bs[(wc*64 + n*16 + hw)*64 + ((kc ^ (hw&7))<<3)];
#pragma unroll
      for (int m=0;m<4;++m)
#pragma unroll
        for (int n=0;n<4;++n)
          acc[m][n] = __builtin_amdgcn_mfma_f32_16x16x32_bf16(af[m], bf[n], acc[m][n], 0,0,0);
    }
    __syncthreads();           // all reads done before next-iter staging
  }

  // ---------------- epilogue ----------------
  float bia[4] = {0.f,0.f,0.f,0.f};
#pragma unroll
  for (int n=0;n<4;++n) {
    const int c = wc*64 + n*16 + hw;
    if (bias0) bia[n] += bias0[c];
    if (bias1) bia[n] += bias1[c];
  }
#pragma unroll
  for (int m=0;m<4;++m)
#pragma unroll
    for (int n=0;n<4;++n)
#pragma unroll
      for (int i=0;i<4;++i) acc[m][n][i] += bia[n];

  if constexpr (EPI == EPI_ELU1) {
#pragma unroll
    for (int m=0;m<4;++m)
#pragma unroll
      for (int n=0;n<4;++n)
#pragma unroll
        for (int i=0;i<4;++i) {
          float v = acc[m][n][i];
          acc[m][n][i] = v > 0.f ? v + 1.f : __expf(v);
        }
  }
  if constexpr (EPI == EPI_RELU) {
#pragma unroll
    for (int m=0;m<4;++m)
#pragma unroll
      for (int n=0;n<4;++n)
#pragma unroll
        for (int i=0;i<4;++i) acc[m][n][i] = fmaxf(acc[m][n][i], 0.f);
  }
  if constexpr (EPI == EPI_DIVZ) {
#pragma unroll
    for (int m=0;m<4;++m) {
      f32x4 z = *(const f32x4*)(Zr + r0 + wr*64 + m*16 + q*4);
#pragma unroll
      for (int i=0;i<4;++i) {
        const float iz = 1.f / z[i];
#pragma unroll
        for (int n=0;n<4;++n) acc[m][n][i] *= iz;
      }
    }
  }

  float mu[4][4], rsg[4][4];
  float lg[4], lb[4];
  if constexpr (EPI == EPI_LN || EPI == EPI_LNRES) {
#pragma unroll
    for (int n=0;n<4;++n) {
      const int c = wc*64 + n*16 + hw;
      lg[n] = lng[c]; lb[n] = lnb[c];
    }
    float s1[4][4], s2[4][4];
#pragma unroll
    for (int m=0;m<4;++m)
#pragma unroll
      for (int i=0;i<4;++i) {
        float s = 0.f, sq = 0.f;
#pragma unroll
        for (int n=0;n<4;++n) { const float v = acc[m][n][i]; s += v; sq += v*v; }
        s1[m][i] = s; s2[m][i] = sq;
      }
#pragma unroll
    for (int off=1; off<16; off<<=1)
#pragma unroll
      for (int m=0;m<4;++m)
#pragma unroll
        for (int i=0;i<4;++i) {
          s1[m][i] += __shfl_xor(s1[m][i], off);
          s2[m][i] += __shfl_xor(s2[m][i], off);
        }
    if (hw == 0) {
#pragma unroll
      for (int m=0;m<4;++m)
#pragma unroll
        for (int i=0;i<4;++i)
          red[wr*64 + m*16 + q*4 + i][wc] = make_float2(s1[m][i], s2[m][i]);
    }
    __syncthreads();
#pragma unroll
    for (int m=0;m<4;++m)
#pragma unroll
      for (int i=0;i<4;++i) {
        float ts = 0.f, tq = 0.f;
#pragma unroll
        for (int ww=0;ww<4;++ww) {
          const float2 v = red[wr*64 + m*16 + q*4 + i][ww];
          ts += v.x; tq += v.y;
        }
        const float mmu = ts * (1.f/256.f);
        float var = tq * (1.f/256.f) - mmu*mmu;
        var = var > 0.f ? var : 0.f;
        mu[m][i]  = mmu;
        rsg[m][i] = rsqrtf(var + 1e-5f);
      }
  }

#pragma unroll
  for (int m=0;m<4;++m) {
#pragma unroll
    for (int i=0;i<4;++i) {
      const int rr = wr*64 + m*16 + q*4 + i;
      const int lr = r0 + rr;
      if (lr >= nrows) continue;
      long rid = 0;
      if constexpr (EPI == EPI_LNRES)
        rid = idxR ? (long)idxR[roff + lr] : (long)(roff + lr);
#pragma unroll
      for (int n=0;n<4;++n) {
        const int c = wc*64 + n*16 + hw;
        float v = acc[m][n][i];
        if constexpr (EPI == EPI_LN || EPI == EPI_LNRES)
          v = (v - mu[m][i]) * rsg[m][i] * lg[n] + lb[n];
        if constexpr (EPI == EPI_LNRES)
          v += b2f(RESB[rid*256 + c]);
        const long coff = (long)(dc0 + lr)*ldc + c;
        if constexpr (OBF16) ((unsigned short*)Cv)[coff] = f2b(v);
        else                 ((float*)Cv)[coff] = v;
      }
    }
  }
}

// ---------------------------------------------------------------- K^T V via MFMA, split-K over rows
__global__ __launch_bounds__(256,2) void ktv_mfma(
    const unsigned short* __restrict__ Kb, const unsigned short* __restrict__ Vb,
    int rows, int rpp, float* __restrict__ pKV)
{
  __shared__ short As[128*64];   // As[a][r] = K[r][a0+a], r swizzled
  __shared__ short Bs[128*64];   // Bs[b][r] = V[r][b0+b]
  const int t  = threadIdx.x;
  const int w  = t >> 6;
  const int l  = t & 63;
  const int q  = l >> 4;
  const int hw = l & 15;
  const int wa = w >> 1, wb = w & 1;
  const int a0 = blockIdx.x << 7;
  const int b0 = blockIdx.y << 7;
  const int p  = blockIdx.z;
  const int rbeg = p * rpp;
  const int rend = min(rows, rbeg + rpp);

  f32x4 acc[4][4];
#pragma unroll
  for (int m=0;m<4;++m)
#pragma unroll
    for (int n=0;n<4;++n) acc[m][n] = (f32x4){0.f,0.f,0.f,0.f};
  float ksum = 0.f;

  for (int r0 = rbeg; r0 < rend; r0 += 64) {
    const int gr = r0 + l;
    const bool valid = gr < rend;
    short8v kf[4], vf[4];
#pragma unroll
    for (int j=0;j<4;++j) {
      if (valid) {
        kf[j] = *(const short8v*)(Kb + (long)gr*256 + a0 + w*32 + j*8);
        vf[j] = *(const short8v*)(Vb + (long)gr*256 + b0 + w*32 + j*8);
      } else {
        kf[j] = (short8v){0,0,0,0,0,0,0,0};
        vf[j] = (short8v){0,0,0,0,0,0,0,0};
      }
    }
    __syncthreads();
#pragma unroll
    for (int j=0;j<4;++j)
#pragma unroll
      for (int e=0;e<8;++e) {
        const int a = w*32 + j*8 + e;
        As[a*64 + (l ^ (e<<3))] = kf[j][e];
        Bs[a*64 + (l ^ (e<<3))] = vf[j][e];
      }
    __syncthreads();

#pragma unroll
    for (int kk=0;kk<2;++kk) {
      const int kc = (kk<<2) + q;
      short8v af[4], bf[4];
#pragma unroll
      for (int m=0;m<4;++m)
        af[m] = *(const short8v*)&As[(wa*64+m*16+hw)*64 + ((kc ^ (hw&7))<<3)];
#pragma unroll
      for (int n=0;n<4;++n)
        bf[n] = *(const short8v*)&Bs[(wb*64+n*16+hw)*64 + ((kc ^ (hw&7))<<3)];
#pragma unroll
      for (int m=0;m<4;++m)
#pragma unroll
        for (int n=0;n<4;++n)
          acc[m][n] = __builtin_amdgcn_mfma_f32_16x16x32_bf16(af[m], bf[n], acc[m][n], 0,0,0);
    }

    if (blockIdx.y == 0 && t < 128) {
#pragma unroll
      for (int kc=0;kc<8;++kc) {
        short8v v = *(const short8v*)&As[t*64 + ((kc ^ (t&7))<<3)];
#pragma unroll
        for (int e=0;e<8;++e) ksum += b2f((unsigned short)v[e]);
      }
    }
  }

  const long base = (long)p * 65792;
#pragma unroll
  for (int m=0;m<4;++m)
#pragma unroll
    for (int i=0;i<4;++i) {
      const int a = a0 + wa*64 + m*16 + q*4 + i;
#pragma unroll
      for (int n=0;n<4;++n) {
        const int b = b0 + wb*64 + n*16 + hw;
        pKV[base + (long)a*256 + b] = acc[m][n][i];
      }
    }
  if (blockIdx.y == 0 && t < 128) pKV[base + 65536 + a0 + t] = ksum;
}

__global__ __launch_bounds__(256) void kv_accum(const float* __restrict__ pKV, int P,
                                                float* __restrict__ KV) {
  const int i = blockIdx.x*256 + threadIdx.x;
  if (i >= 65792) return;
  float s = 0.f;
  for (int p=0;p<P;++p) s += pKV[(long)p*65792 + i];
  KV[i] += s;
}

// Z[r] = Q[r,:] . Ksum + 1e-6
__global__ __launch_bounds__(256) void row_dot(const unsigned short* __restrict__ Q,
    const float* __restrict__ Ksum, float* __restrict__ Z, int rows) {
  const long gid = (long)blockIdx.x*256 + threadIdx.x;
  const int row = (int)(gid >> 6);
  const int lane = (int)(gid & 63);
  if (row >= rows) return;
  short4v q4 = *(const short4v*)(Q + (long)row*256 + lane*4);
  const float4 k = *(const float4*)(Ksum + lane*4);
  float s = b2f((unsigned short)q4[0])*k.x + b2f((unsigned short)q4[1])*k.y
          + b2f((unsigned short)q4[2])*k.z + b2f((unsigned short)q4[3])*k.w;
#pragma unroll
  for (int off=32; off; off>>=1) s += __shfl_xor(s, off);
  if (lane==0) Z[row] = s + 1e-6f;
}

// Conv1d(2->1, k=3, pad=1) over gathered src/dst rows of ORIGINAL h_nodes -> bf16
__global__ __launch_bounds__(256) void conv_rows(const float* __restrict__ h,
    const int* __restrict__ gs, const int* __restrict__ gd, int gr0, int rows,
    const float* __restrict__ cw, const float* __restrict__ cb,
    unsigned short* __restrict__ Cc) {
  const int r = blockIdx.x;
  if (r >= rows) return;
  const int d = threadIdx.x;
  const float* sr = h + (long)gs[gr0+r]*256;
  const float* dr = h + (long)gd[gr0+r]*256;
  const float sm = d>0   ? sr[d-1] : 0.f;
  const float sp = d<255 ? sr[d+1] : 0.f;
  const float dm = d>0   ? dr[d-1] : 0.f;
  const float dp = d<255 ? dr[d+1] : 0.f;
  Cc[(long)r*256 + d] = f2b(cb[0] + cw[0]*sm + cw[1]*sr[d] + cw[2]*sp
                                  + cw[3]*dm + cw[4]*dr[d] + cw[5]*dp);
}

// ---------------------------------------------------------------- BatchNorm (train), fp32 in place
__global__ __launch_bounds__(256) void bn_stats(const float* __restrict__ X, long rows,
    int rpb, float* __restrict__ part) {
  const int p = blockIdx.x;
  const int c = threadIdx.x;
  long r0 = (long)p*rpb;
  long r1 = r0 + rpb; if (r1 > rows) r1 = rows;
  float s=0.f, s2=0.f;
  for (long r=r0; r<r1; ++r) { const float v = X[r*256 + c]; s += v; s2 += v*v; }
  part[(long)p*512 + c] = s;
  part[(long)p*512 + 256 + c] = s2;
}

__global__ __launch_bounds__(256) void bn_finalize(const float* __restrict__ part, int P,
    long rows, const float* __restrict__ g, const float* __restrict__ b,
    float* __restrict__ scale, float* __restrict__ shift) {
  const int c = threadIdx.x;
  float s=0.f, s2=0.f;
  for (int p=0;p<P;++p) { s += part[(long)p*512 + c]; s2 += part[(long)p*512 + 256 + c]; }
  const float inv = 1.f/(float)rows;
  const float mu = s*inv;
  float var = s2*inv - mu*mu;
  var = var > 0.f ? var : 0.f;
  const float rs = rsqrtf(var + 1e-5f);
  scale[c] = g[c]*rs;
  shift[c] = b[c] - mu*g[c]*rs;
}

template<bool R>
__global__ __launch_bounds__(256) void bn_apply(float* __restrict__ X, long rows,
    const float* __restrict__ sc, const float* __restrict__ sh) {
  const long n4 = rows*64;
  long i = (long)blockIdx.x*256 + threadIdx.x;
  const long st = (long)gridDim.x*256;
  for (; i<n4; i+=st) {
    const int cq = (int)(i & 63);
    float4 v = ((float4*)X)[i];
    const float4 s4 = ((const float4*)sc)[cq];
    const float4 h4 = ((const float4*)sh)[cq];
    v.x = v.x*s4.x + h4.x; v.y = v.y*s4.y + h4.y;
    v.z = v.z*s4.z + h4.z; v.w = v.w*s4.w + h4.w;
    if (R) { v.x=fmaxf(v.x,0.f); v.y=fmaxf(v.y,0.f); v.z=fmaxf(v.z,0.f); v.w=fmaxf(v.w,0.f); }
    ((float4*)X)[i] = v;
  }
}

// ---------------------------------------------------------------- host-side
struct Ctx {
  const unsigned short *WqT,*WkT,*WvT,*WmT,*mw1T,*mw2T,*WfT;
  const float *bm,*l1g,*l1b,*mb1,*mb2,*l2g,*l2b,*b4,*b2,*conv_w,*conv_b;
  const float *h_nodes;
  unsigned short* h_nb;
  unsigned short *bufA,*bufB,*bufC,*bufY;
  float *Zb,*pKV,*KV;
  unsigned short* KVT;
  long CH;
  hipStream_t st;
};

static void run_enc(const Ctx& c, long L, long S,
                    const unsigned short* Asrc, const int* iA,
                    const unsigned short* Bsrc, const int* iB,
                    unsigned short* outB, float* outF, bool fuse,
                    const int* g_src, const int* g_dst, float* lr_e)
{
  hipMemsetAsync(c.KV, 0, 65792*sizeof(float), c.st);
  for (long s0=0; s0<S; s0+=c.CH) {
    const int cnt = (int)((S-s0 < c.CH) ? (S-s0) : c.CH);
    const int gb = (cnt+127)/128;
    gemm_mf<EPI_ELU1,true><<<gb,512,0,c.st>>>(Bsrc,256,iB,(int)s0, nullptr,0, 256,256,
        c.WkT,256, nullptr,nullptr, nullptr, nullptr,nullptr, nullptr,nullptr,0,
        c.bufA,256,0,cnt);
    gemm_mf<EPI_NONE,true><<<gb,512,0,c.st>>>(Bsrc,256,iB,(int)s0, nullptr,0, 256,256,
        c.WvT,256, nullptr,nullptr, nullptr, nullptr,nullptr, nullptr,nullptr,0,
        c.bufB,256,0,cnt);
    const int P = (cnt+2047)/2048;
    ktv_mfma<<<dim3(2,2,P),256,0,c.st>>>(c.bufA,c.bufB,cnt,2048,c.pKV);
    kv_accum<<<257,256,0,c.st>>>(c.pKV,P,c.KV);
  }
  wt_build<<<dim3(4,4),256,0,c.st>>>(c.KV,256,256,c.KVT,256,0);
  for (long l0=0; l0<L; l0+=c.CH) {
    const int cnt = (int)((L-l0 < c.CH) ? (L-l0) : c.CH);
    const int gb = (cnt+127)/128;
    gemm_mf<EPI_ELU1,true><<<gb,512,0,c.st>>>(Asrc,256,iA,(int)l0, nullptr,0, 256,256,
        c.WqT,256, nullptr,nullptr, nullptr, nullptr,nullptr, nullptr,nullptr,0,
        c.bufA,256,0,cnt);
    row_dot<<<(cnt+3)/4,256,0,c.st>>>(c.bufA, c.KV+65536, c.Zb, cnt);
    gemm_mf<EPI_DIVZ,true><<<gb,512,0,c.st>>>(c.bufA,256,nullptr,0, nullptr,0, 256,256,
        c.KVT,256, nullptr,nullptr, c.Zb, nullptr,nullptr, nullptr,nullptr,0,
        c.bufB,256,0,cnt);
    gemm_mf<EPI_LN,true><<<gb,512,0,c.st>>>(c.bufB,256,nullptr,0, nullptr,0, 256,256,
        c.WmT,256, c.bm,nullptr, nullptr, c.l1g,c.l1b, nullptr,nullptr,0,
        c.bufC,256,0,cnt);
    gemm_mf<EPI_RELU,true><<<gb,512,0,c.st>>>(Asrc,256,iA,(int)l0, c.bufC,256, 512,256,
        c.mw1T,512, c.mb1,nullptr, nullptr, nullptr,nullptr, nullptr,nullptr,0,
        c.bufY,512,0,cnt);
    gemm_mf<EPI_RELU,true><<<gb,512,0,c.st>>>(Asrc,256,iA,(int)l0, c.bufC,256, 512,256,
        c.mw1T+(long)256*512,512, c.mb1+256,nullptr, nullptr, nullptr,nullptr, nullptr,nullptr,0,
        c.bufY+256,512,0,cnt);
    if (fuse) {
      gemm_mf<EPI_LNRES,true><<<gb,512,0,c.st>>>(c.bufY,512,nullptr,0, nullptr,0, 512,512,
          c.mw2T,512, c.mb2,nullptr, nullptr, c.l2g,c.l2b, c.h_nb,iA,(int)l0,
          c.bufB,256,0,cnt);
      conv_rows<<<cnt,256,0,c.st>>>(c.h_nodes, g_src, g_dst, (int)l0, cnt, c.conv_w, c.conv_b, c.bufA);
      gemm_mf<EPI_NONE,false><<<gb,512,0,c.st>>>(c.bufB,256,nullptr,0, c.bufA,256, 512,256,
          c.WfT,512, c.b4,c.b2, nullptr, nullptr,nullptr, nullptr,nullptr,0,
          lr_e,256,(int)l0,cnt);
    } else if (outF) {
      gemm_mf<EPI_LNRES,false><<<gb,512,0,c.st>>>(c.bufY,512,nullptr,0, nullptr,0, 512,512,
          c.mw2T,512, c.mb2,nullptr, nullptr, c.l2g,c.l2b, c.h_nb,iA,(int)l0,
          outF,256,(int)l0,cnt);
    } else {
      gemm_mf<EPI_LNRES,true><<<gb,512,0,c.st>>>(c.bufY,512,nullptr,0, nullptr,0, 512,512,
          c.mw2T,512, c.mb2,nullptr, nullptr, c.l2g,c.l2b, c.h_nb,iA,(int)l0,
          outB,256,(int)l0,cnt);
    }
  }
}

extern "C" void kernel_launch(void* const* d_in, const int* in_sizes, int n_in,
                              void* d_out, int out_size, void* d_ws, size_t ws_size,
                              hipStream_t stream) {
  const float* h_nodes = (const float*)d_in[0];
  const float* s_u     = (const float*)d_in[1];
  const int*   g_src   = (const int*)d_in[2];
  const int*   g_dst   = (const int*)d_in[3];
  const int*   s_src   = (const int*)d_in[4];
  const int*   s_dst   = (const int*)d_in[5];
  const float* conv_w  = (const float*)d_in[6];
  const float* conv_b  = (const float*)d_in[7];
  const float* W2      = (const float*)d_in[8];
  const float* b2      = (const float*)d_in[9];
  const float* W4      = (const float*)d_in[10];
  const float* b4      = (const float*)d_in[11];
  const float* bn_g    = (const float*)d_in[12];
  const float* bn_b    = (const float*)d_in[13];
  const float* Wq      = (const float*)d_in[14];
  const float* Wk      = (const float*)d_in[15];
  const float* Wv      = (const float*)d_in[16];
  const float* Wm      = (const float*)d_in[17];
  const float* bm      = (const float*)d_in[18];
  const float* l1g     = (const float*)d_in[19];
  const float* l1b     = (const float*)d_in[20];
  const float* mw1     = (const float*)d_in[21];
  const float* mb1     = (const float*)d_in[22];
  const float* mw2     = (const float*)d_in[23];
  const float* mb2     = (const float*)d_in[24];
  const float* l2g     = (const float*)d_in[25];
  const float* l2b     = (const float*)d_in[26];
  (void)in_sizes; (void)n_in; (void)out_size;

  float* lr_e = (float*)d_out;                 // [E,256]
  float* soc  = lr_e + (size_t)En*256;         // [ES,256]

  char* base = (char*)d_ws;
  size_t off = 0;
  auto carve = [&](size_t bytes)->void* {
    void* p = (void*)(base + off);
    off = (off + bytes + 255) & ~(size_t)255;
    return p;
  };
  unsigned short* h_nb = (unsigned short*)carve((size_t)Mn*256*2);
  unsigned short* s_ub = (unsigned short*)carve((size_t)Nn*256*2);
  unsigned short* WqT  = (unsigned short*)carve(65536*2);
  unsigned short* WkT  = (unsigned short*)carve(65536*2);
  unsigned short* WvT  = (unsigned short*)carve(65536*2);
  unsigned short* WmT  = (unsigned short*)carve(65536*2);
  unsigned short* mw1T = (unsigned short*)carve(262144*2);
  unsigned short* mw2T = (unsigned short*)carve(131072*2);
  unsigned short* WfT  = (unsigned short*)carve(131072*2);
  float* KV            = (float*)carve(65792*4);
  unsigned short* KVT  = (unsigned short*)carve(65536*2);
  float* bnpart        = (float*)carve((size_t)512*512*4);
  float* bnscale       = (float*)carve(256*4);
  float* bnshift       = (float*)carve(256*4);

  const size_t remain = ws_size > off ? ws_size - off : 0;
  long CH = (long)(remain / 2629632) * 1024;
  if (CH > 204800) CH = 204800;
  if (CH < 2048)   CH = 2048;
  unsigned short* bufA = (unsigned short*)carve((size_t)CH*256*2);
  unsigned short* bufB = (unsigned short*)carve((size_t)CH*256*2);
  unsigned short* bufC = (unsigned short*)carve((size_t)CH*256*2);
  unsigned short* bufY = (unsigned short*)carve((size_t)CH*512*2);
  float* Zb            = (float*)carve((size_t)CH*4);
  float* pKV           = (float*)bufY;          // phase-A only; bufY is phase-B only

  // ---- pre-pass: converts + weight transposes
  cvt_b<<<2048,256,0,stream>>>(h_nodes, h_nb, (long)Mn*256);
  cvt_b<<<1024,256,0,stream>>>(s_u, s_ub, (long)Nn*256);
  wt_build<<<dim3(4,4),256,0,stream>>>(Wq, 256,256, WqT, 256, 0);
  wt_build<<<dim3(4,4),256,0,stream>>>(Wk, 256,256, WkT, 256, 0);
  wt_build<<<dim3(4,4),256,0,stream>>>(Wv, 256,256, WvT, 256, 0);
  wt_build<<<dim3(4,4),256,0,stream>>>(Wm, 256,256, WmT, 256, 0);
  wt_build<<<dim3(8,8),256,0,stream>>>(mw1, 512,512, mw1T, 512, 0);
  wt_build<<<dim3(4,8),256,0,stream>>>(mw2, 512,256, mw2T, 512, 0);
  wt_build<<<dim3(4,4),256,0,stream>>>(W4, 256,256, WfT, 512, 0);
  wt_build<<<dim3(4,4),256,0,stream>>>(W2, 256,256, WfT, 512, 256);

  Ctx c;
  c.WqT=WqT; c.WkT=WkT; c.WvT=WvT; c.WmT=WmT; c.mw1T=mw1T; c.mw2T=mw2T; c.WfT=WfT;
  c.bm=bm; c.l1g=l1g; c.l1b=l1b; c.mb1=mb1; c.mb2=mb2; c.l2g=l2g; c.l2b=l2b;
  c.b4=b4; c.b2=b2; c.conv_w=conv_w; c.conv_b=conv_b;
  c.h_nodes=h_nodes; c.h_nb=h_nb;
  c.bufA=bufA; c.bufB=bufB; c.bufC=bufC; c.bufY=bufY;
  c.Zb=Zb; c.pKV=pKV; c.KV=KV; c.KVT=KVT;
  c.CH=CH; c.st=stream;

  // ---- 1. x = enc(h_nodes[:N], s_u) -> h_nb[0:N) (bf16, in place)
  run_enc(c, Nn, Nn, h_nb, nullptr, s_ub, nullptr, h_nb, nullptr, false, nullptr, nullptr, nullptr);
  // ---- 2. edge = enc(h_n[g_src], h_n[g_dst]); fused with conv + W4/W2 -> lr_e (fp32, pre-BN)
  run_enc(c, En, En, h_nb, g_src, h_nb, g_dst, nullptr, nullptr, true, g_src, g_dst, lr_e);
  // ---- 3. social = enc(x[s_src], x[s_dst]) -> soc (fp32, pre-BN)
  run_enc(c, ESn, ESn, h_nb, s_src, h_nb, s_dst, nullptr, soc, false, nullptr, nullptr, nullptr);

  // ---- 4. lr_e = relu(BN(lr_e))
  {
    const int P3 = (En+511)/512;
    bn_stats<<<P3,256,0,stream>>>(lr_e,(long)En,512,bnpart);
    bn_finalize<<<1,256,0,stream>>>(bnpart,P3,(long)En,bn_g,bn_b,bnscale,bnshift);
    bn_apply<true><<<2048,256,0,stream>>>(lr_e,(long)En,bnscale,bnshift);
  }
  // ---- 5. soc = BN(soc)
  {
    const int P4 = (ESn+511)/512;
    bn_stats<<<P4,256,0,stream>>>(soc,(long)ESn,512,bnpart);
    bn_finalize<<<1,256,0,stream>>>(bnpart,P4,(long)ESn,bn_g,bn_b,bnscale,bnshift);
    bn_apply<false><<<2048,256,0,stream>>>(soc,(long)ESn,bnscale,bnshift);
  }
}